// Round 13
// baseline (718.872 us; speedup 1.0000x reference)
//
#include <hip/hip_runtime.h>
#include <math.h>

#define Bz 64
#define Sz 200
#define Dz 128
#define NQz 50000
#define NCz 1000
#define MCz 4
#define Kz 10
#define Tz 199            // S-1 scan steps
#define NSz (Bz*Tz)       // 12736 (b,t) slots; 12736/64 = 199 exactly
#define NEz (NQz*MCz)     // 200000 edges
#define KTpad 256         // padded t-dim of transposed kqt

// ---------------- GNN: CSR build + per-concept aggregation ----------------
__global__ void k_count(const int* __restrict__ qt, int* __restrict__ cnt) {
    int e = blockIdx.x*256 + threadIdx.x;
    if (e < NEz) atomicAdd(&cnt[qt[e]], 1);
}

__global__ void k_offs(const int* __restrict__ cnt, int* __restrict__ offs) {
    __shared__ int s[1024];
    int tid = threadIdx.x;
    s[tid] = (tid < NCz) ? cnt[tid] : 0;
    __syncthreads();
    for (int off = 1; off < 1024; off <<= 1) {
        int add = (tid >= off) ? s[tid - off] : 0;
        __syncthreads();
        s[tid] += add;
        __syncthreads();
    }
    if (tid < NCz) offs[tid + 1] = s[tid];
    if (tid == 0) offs[0] = 0;
}

__global__ void k_fill(const int* __restrict__ qt, const int* __restrict__ offs,
                       int* __restrict__ fill, int* __restrict__ edge_q) {
    int e = blockIdx.x*256 + threadIdx.x;
    if (e < NEz) {
        int c = qt[e];
        int pos = atomicAdd(&fill[c], 1);
        edge_q[offs[c] + pos] = e >> 2;     // question id
    }
}

// m2[c] = mean over edges (q->c) of ( emb_q[q] + 0.25*sum_m emb_c[q_table[q][m]] )
__global__ void k_m2(const int* __restrict__ qt, const int* __restrict__ offs,
                     const int* __restrict__ edge_q,
                     const float* __restrict__ emb_q, const float* __restrict__ emb_c,
                     float* __restrict__ m2) {
    int c = blockIdx.x;
    int g = threadIdx.x >> 7;      // 0..3
    int d = threadIdx.x & 127;
    int e0 = offs[c], e1 = offs[c+1];
    float acc = 0.f;
    for (int e = e0 + g; e < e1; e += 4) {
        int q = edge_q[e];
        const int* t4 = qt + q*4;
        int c0 = t4[0], c1 = t4[1], c2 = t4[2], c3 = t4[3];
        acc += emb_q[q*128 + d]
             + 0.25f*(emb_c[c0*128+d] + emb_c[c1*128+d] + emb_c[c2*128+d] + emb_c[c3*128+d]);
    }
    __shared__ float ps[4][128];
    ps[g][d] = acc;
    __syncthreads();
    if (g == 0) {
        float tot = ps[0][d] + ps[1][d] + ps[2][d] + ps[3][d];
        float cn = (float)(e1 - e0);
        m2[c*128 + d] = tot / fmaxf(cn, 1.0f);
    }
}

// ---------------- small 128x128 matmuls (weight folding) ----------------
template<bool TR>
__global__ void k_mm128(const float* __restrict__ X, const float* __restrict__ Y,
                        float* __restrict__ out) {
    int r = blockIdx.x, c = threadIdx.x;
    float acc = 0.f;
    for (int e = 0; e < 128; ++e) acc += X[r*128 + e] * Y[e*128 + c];
    if (TR) out[c*128 + r] = acc;           // store transposed (Mt[d][r] = M[r][d])
    else    out[r*128 + c] = acc;
}

// gr[rt][r] = bih1[r] + sum_e emb_r[rt][e]*Wih1[r][128+e]   (response-part of gi1, bias folded)
__global__ void k_gr(const float* __restrict__ emb_r, const float* __restrict__ Wih1,
                     const float* __restrict__ bih1, float* __restrict__ gr) {
    int rt = threadIdx.x / 384, r = threadIdx.x % 384;   // block 768
    float acc = bih1[r];
    for (int e = 0; e < 128; ++e) acc += emb_r[rt*128 + e] * Wih1[r*256 + 128 + e];
    gr[rt*384 + r] = acc;
}

// Bkq rows 0..127: G = Wq^T Wk;  row 128: wkb = Wk^T bq;  row 129: Ww[0][128:256]
// biaskq: 0..127: Wq^T bk;  128: bq.bk;  129: bw
__global__ void k_bkq(const float* __restrict__ Wq, const float* __restrict__ Wk,
                      const float* __restrict__ bq, const float* __restrict__ bk,
                      const float* __restrict__ Ww, const float* __restrict__ bw,
                      float* __restrict__ Bkq, float* __restrict__ biaskq) {
    int r = blockIdx.x, d = threadIdx.x;
    if (r < 128) {
        float acc = 0.f;
        for (int n = 0; n < 128; ++n) acc += Wq[n*128 + r] * Wk[n*128 + d];
        Bkq[r*128 + d] = acc;
        if (d == 0) {
            float b0 = 0.f;
            for (int n = 0; n < 128; ++n) b0 += Wq[n*128 + r] * bk[n];
            biaskq[r] = b0;
        }
    } else if (r == 128) {
        float acc = 0.f;
        for (int n = 0; n < 128; ++n) acc += bq[n] * Wk[n*128 + d];
        Bkq[128*128 + d] = acc;
        if (d == 0) {
            float c0 = 0.f;
            for (int n = 0; n < 128; ++n) c0 += bq[n] * bk[n];
            biaskq[128] = c0;
        }
    } else {
        Bkq[129*128 + d] = Ww[128 + d];
        if (d == 0) biaskq[129] = bw[0];
    }
}

// ---------------- per-slot GNN question embedding ----------------
__global__ void k_eq(const float* __restrict__ Mt_g, const float* __restrict__ bagg,
                     const float* __restrict__ emb_q, const float* __restrict__ emb_c,
                     const float* __restrict__ m2, const int* __restrict__ qseq,
                     const int* __restrict__ mseq, const int* __restrict__ qt,
                     float* __restrict__ eq) {
    __shared__ float Mt[128*128];
    __shared__ float ub[2][128];
    int tid = threadIdx.x;
    for (int i = tid; i < 128*128/4; i += 256)
        ((float4*)Mt)[i] = ((const float4*)Mt_g)[i];
    __syncthreads();
    int g = tid >> 7, d = tid & 127;
    for (int it = 0; it < 8; ++it) {
        int slot = blockIdx.x*16 + it*2 + g;            // grid 796 -> slots exactly cover NSz
        int b = slot / Tz, t = slot % Tz;
        int q = qseq[b*Sz + t];
        int msk = mseq[b*Sz + t];
        if (msk) {
            const int* t4 = qt + q*4;
            int c0 = t4[0], c1 = t4[1], c2 = t4[2], c3 = t4[3];
            ub[g][d] = emb_q[q*128 + d]
                     + 0.5f *(emb_c[c0*128+d] + emb_c[c1*128+d] + emb_c[c2*128+d] + emb_c[c3*128+d])
                     + 0.25f*(m2[c0*128+d]  + m2[c1*128+d]  + m2[c2*128+d]  + m2[c3*128+d]);
        }
        __syncthreads();
        if (msk) {
            float acc = bagg[d];
            const float* urow = ub[g];
            for (int e = 0; e < 128; ++e) acc += Mt[e*128 + d] * urow[e];
            eq[slot*128 + d] = tanhf(acc);
        } else {
            eq[slot*128 + d] = emb_q[q*128 + d];
        }
        __syncthreads();
    }
}

// ---------------- numeric helpers ----------------
__device__ __forceinline__ float bf_lo(unsigned u){ return __uint_as_float(u << 16); }
__device__ __forceinline__ float bf_hi(unsigned u){ return __uint_as_float(u & 0xffff0000u); }
__device__ __forceinline__ unsigned f2bf(float x){          // RNE round to bf16 (bits in low 16)
    unsigned u = __float_as_uint(x);
    return (u + 0x7fffu + ((u >> 16) & 1u)) >> 16;
}
__device__ __forceinline__ unsigned pk2(float a, float b){
    return f2bf(a) | (f2bf(b) << 16);
}
__device__ __forceinline__ float rcpf(float x){ return __builtin_amdgcn_rcpf(x); }
__device__ __forceinline__ float sigm(float x){ return rcpf(1.f + __expf(-x)); }
__device__ __forceinline__ float tanh_fast(float x){
    float e = __expf(2.f*x);
    return 1.f - 2.f*rcpf(e + 1.f);
}

#if __has_builtin(__builtin_amdgcn_fdot2_f32_bf16)
typedef __attribute__((ext_vector_type(2))) short short2v;
__device__ __forceinline__ float bdot2(unsigned w, unsigned h, float acc) {
    return __builtin_amdgcn_fdot2_f32_bf16(__builtin_bit_cast(short2v, w),
                                           __builtin_bit_cast(short2v, h), acc, false);
}
#else
__device__ __forceinline__ float bdot2(unsigned w, unsigned h, float acc) {
    return acc + bf_lo(w)*bf_lo(h) + bf_hi(w)*bf_hi(h);
}
#endif

// packed fp32 FMA (VOP3P): acc.lo += k.lo*q_sel, acc.hi += k.hi*q_sel.
// op_sel broadcast of one q component avoids splat moves.
typedef __attribute__((ext_vector_type(2))) float v2f;
__device__ __forceinline__ void pkfma_lo(v2f &acc, v2f k, v2f q) {   // q.lo broadcast
    asm("v_pk_fma_f32 %0, %1, %2, %0 op_sel_hi:[1,0,1]"
        : "+v"(acc) : "v"(k), "v"(q));
}
__device__ __forceinline__ void pkfma_hi(v2f &acc, v2f k, v2f q) {   // q.hi broadcast
    asm("v_pk_fma_f32 %0, %1, %2, %0 op_sel:[0,1,0] op_sel_hi:[1,1,1]"
        : "+v"(acc) : "v"(k), "v"(q));
}

// ---------------- tiled GEMM: C[s][n] = A[s][:128] . Bm[n][:128] + epilogue ----------------
// MODE 0: + bias[n] (gi2)   MODE 1: + gr[rt(s)][n] (gi1)
// MODE 2: + bias[n], store TRANSPOSED: C[(b*132+n)*KTpad + t]  (kqt path)
// DOT2 1: bf16-pair LDS staging + v_dot2 inner loop (gi GEMMs only).
template<int MODE, int DOT2>
__global__ void k_gemm(const float* __restrict__ A, const float* __restrict__ Bm,
                       int ldb, int nB, float* __restrict__ C, int ldc,
                       const float* __restrict__ bias, const float* __restrict__ gr,
                       const int* __restrict__ cseq) {
    __shared__ int rtb[64];
    int tx = threadIdx.x, ty = threadIdx.y;
    int tid = ty*16 + tx;
    int m0 = blockIdx.x * 64;
    int n0 = blockIdx.y * 64;
    if (MODE == 1 && tid < 64) {
        int s = m0 + tid;
        int b = s / Tz, t = s % Tz;
        rtb[tid] = cseq[b*Sz + t];
    }
    float acc[4][4];
    #pragma unroll
    for (int i = 0; i < 4; ++i)
        #pragma unroll
        for (int j = 0; j < 4; ++j) acc[i][j] = 0.f;

    if (DOT2) {
        __shared__ unsigned As[64][17];     // 16 bf16-pairs per row (+1 pad)
        __shared__ unsigned Bs[64][17];
        for (int kc = 0; kc < 128; kc += 32) {
            #pragma unroll
            for (int l = 0; l < 2; ++l) {
                int v = tid*2 + l;                 // 0..511
                int row = v >> 3, c4 = (v & 7) << 2;
                int p0 = (kc + c4) >> 1 & 15;      // pair index within tile
                float4 av = *(const float4*)(A + (size_t)(m0+row)*128 + kc + c4);
                As[row][p0]   = pk2(av.x, av.y);
                As[row][p0+1] = pk2(av.z, av.w);
                int nrow = n0 + row;
                float4 bv = make_float4(0.f, 0.f, 0.f, 0.f);
                if (nrow < nB) bv = *(const float4*)(Bm + (size_t)nrow*ldb + kc + c4);
                Bs[row][p0]   = pk2(bv.x, bv.y);
                Bs[row][p0+1] = pk2(bv.z, bv.w);
            }
            __syncthreads();
            #pragma unroll 4
            for (int kp = 0; kp < 16; ++kp) {
                unsigned av[4], bv[4];
                #pragma unroll
                for (int i = 0; i < 4; ++i) av[i] = As[ty*4+i][kp];
                #pragma unroll
                for (int j = 0; j < 4; ++j) bv[j] = Bs[tx*4+j][kp];
                #pragma unroll
                for (int i = 0; i < 4; ++i)
                    #pragma unroll
                    for (int j = 0; j < 4; ++j) acc[i][j] = bdot2(av[i], bv[j], acc[i][j]);
            }
            __syncthreads();
        }
    } else {
        __shared__ float Asf[64][33];
        __shared__ float Bsf[64][33];
        for (int kc = 0; kc < 128; kc += 32) {
            #pragma unroll
            for (int l = 0; l < 2; ++l) {
                int v = tid*2 + l;                 // 0..511
                int row = v >> 3, c4 = (v & 7) << 2;
                float4 av = *(const float4*)(A + (size_t)(m0+row)*128 + kc + c4);
                Asf[row][c4+0] = av.x; Asf[row][c4+1] = av.y; Asf[row][c4+2] = av.z; Asf[row][c4+3] = av.w;
                int nrow = n0 + row;
                float4 bv = make_float4(0.f, 0.f, 0.f, 0.f);
                if (nrow < nB) bv = *(const float4*)(Bm + (size_t)nrow*ldb + kc + c4);
                Bsf[row][c4+0] = bv.x; Bsf[row][c4+1] = bv.y; Bsf[row][c4+2] = bv.z; Bsf[row][c4+3] = bv.w;
            }
            __syncthreads();
            #pragma unroll 8
            for (int k = 0; k < 32; ++k) {
                float av[4], bv[4];
                #pragma unroll
                for (int i = 0; i < 4; ++i) av[i] = Asf[ty*4+i][k];
                #pragma unroll
                for (int j = 0; j < 4; ++j) bv[j] = Bsf[tx*4+j][k];
                #pragma unroll
                for (int i = 0; i < 4; ++i)
                    #pragma unroll
                    for (int j = 0; j < 4; ++j) acc[i][j] += av[i]*bv[j];
            }
            __syncthreads();
        }
    }
    #pragma unroll
    for (int i = 0; i < 4; ++i) {
        int s = m0 + ty*4 + i;
        if (MODE == 2) {
            int bb = s / Tz, tt = s - ((int)(s / Tz))*Tz;
            #pragma unroll
            for (int j = 0; j < 4; ++j) {
                int col = n0 + tx*4 + j;
                if (col < nB)
                    C[((size_t)bb*132 + col)*KTpad + tt] = acc[i][j] + bias[col];
            }
        } else {
            #pragma unroll
            for (int j = 0; j < 4; ++j) {
                int col = n0 + tx*4 + j;
                if (col < nB) {
                    float v = acc[i][j];
                    if (MODE == 0) v += bias[col];
                    else           v += gr[rtb[ty*4+i]*384 + col];
                    C[(size_t)s*ldc + col] = v;
                }
            }
        }
    }
}

// ---------------- single-layer GRU scan: 2 batch-chains per block ----------------
// 384 threads; thread r holds Whh row r (64 packed-bf16 regs, shared by BOTH chains).
// Per step: 128 dot2 (2 chains) + 16 uniform b128 LDS; gates on 128 threads (ch=tid>>6);
// same 2 barriers serve 2 chains -> barrier/LDS-latency cost amortized 2x. 32 blocks.
__global__ void __launch_bounds__(384, 1)
k_scan(const float* __restrict__ gi, const float* __restrict__ Whh,
       const float* __restrict__ bhh, float* __restrict__ hout) {
    int b0 = blockIdx.x*2, tid = threadIdx.x;

    unsigned w[64];
    {
        const float4* w4 = (const float4*)(Whh + (size_t)tid*128);
        #pragma unroll
        for (int k = 0; k < 32; ++k) {
            float4 v = w4[k];
            w[2*k] = pk2(v.x, v.y); w[2*k+1] = pk2(v.z, v.w);
        }
    }
    float bb = bhh[tid];

    __shared__ unsigned hb[2][64];        // h packed bf16 (128 units) per chain
    __shared__ float gh[2][384];
    if (tid < 128) hb[tid>>6][tid&63] = 0u;

    float g0=0.f,g1=0.f,g2=0.f,g3=0.f,g4=0.f,g5=0.f;
    if (tid < 128) {
        const float2* gp = (const float2*)(gi + (size_t)((b0 + (tid>>6))*Tz)*384);
        int u = tid & 63;
        float2 x0 = gp[u], x1 = gp[u+64], x2 = gp[u+128];
        g0=x0.x; g1=x0.y; g2=x1.x; g3=x1.y; g4=x2.x; g5=x2.y;
    }
    __syncthreads();

    const uint4* hv0 = (const uint4*)hb[0];
    const uint4* hv1 = (const uint4*)hb[1];

    for (int t = 0; t < Tz; ++t) {
        float n0=0.f,n1=0.f,n2=0.f,n3=0.f,n4=0.f,n5=0.f;
        if (tid < 128 && t + 1 < Tz) {                 // prefetch next step's input gates
            const float2* gp = (const float2*)(gi + (size_t)((b0 + (tid>>6))*Tz + t + 1)*384);
            int u = tid & 63;
            float2 x0 = gp[u], x1 = gp[u+64], x2 = gp[u+128];
            n0=x0.x; n1=x0.y; n2=x1.x; n3=x1.y; n4=x2.x; n5=x2.y;
        }
        // dots for BOTH chains: 16 uniform b128 reads + 128 dot2
        float a0=0.f, a1=0.f, a2=0.f, a3=0.f;   // chain 0
        float c0=0.f, c1=0.f, c2=0.f, c3=0.f;   // chain 1
        #pragma unroll
        for (int k = 0; k < 8; ++k) {
            uint4 hp = hv0[k];
            uint4 hq = hv1[k];
            a0 = bdot2(w[4*k+0], hp.x, a0);
            a1 = bdot2(w[4*k+1], hp.y, a1);
            a2 = bdot2(w[4*k+2], hp.z, a2);
            a3 = bdot2(w[4*k+3], hp.w, a3);
            c0 = bdot2(w[4*k+0], hq.x, c0);
            c1 = bdot2(w[4*k+1], hq.y, c1);
            c2 = bdot2(w[4*k+2], hq.z, c2);
            c3 = bdot2(w[4*k+3], hq.w, c3);
        }
        gh[0][tid] = bb + ((a0+a1)+(a2+a3));
        gh[1][tid] = bb + ((c0+c1)+(c2+c3));
        __syncthreads();
        if (tid < 128) {   // gate phase: chain = tid>>6, 2 units per thread
            int ch = tid >> 6;
            int u = 2*(tid & 63);
            unsigned hp = hb[ch][tid & 63];
            const float* ghc = gh[ch];
            float r0 = sigm(g0 + ghc[u]);
            float r1 = sigm(g1 + ghc[u+1]);
            float z0 = sigm(g2 + ghc[u+128]);
            float z1 = sigm(g3 + ghc[u+129]);
            float q0 = tanh_fast(g4 + r0*ghc[u+256]);
            float q1 = tanh_fast(g5 + r1*ghc[u+257]);
            float h0  = (1.f - z0)*q0 + z0*bf_lo(hp);
            float h1v = (1.f - z1)*q1 + z1*bf_hi(hp);
            hb[ch][tid & 63] = pk2(h0, h1v);
            ((float2*)(hout + (size_t)((b0+ch)*Tz + t)*128))[tid & 63] = make_float2(h0, h1v);
        }
        g0=n0; g1=n1; g2=n2; g3=n3; g4=n4; g5=n5;
        __syncthreads();
    }
}

// ---------------- attention + top-k + output (kqt + packed-fp32 FMA) ----------------
// Lane owns j = 4*lane..4*lane+3 (contiguous in kqt): per d-row one coalesced float4.
// Hot loop uses v_pk_fma_f32 (2 MACs/instr, op_sel q-broadcast): 40 pk_fma per c-chunk
// vs r12's 80 scalar FMA -> halves the VALU-issue bottleneck the r12 counters exposed.
__global__ void __launch_bounds__(256, 1)
k_attn(const float* __restrict__ kqt, const int* __restrict__ qseq,
       const int* __restrict__ qt, const float* __restrict__ emb_q,
       const float* __restrict__ emb_c, const float* __restrict__ Ww,
       float* __restrict__ out) {
    int wid  = threadIdx.x >> 6;
    int lane = threadIdx.x & 63;
    int b = blockIdx.y;
    int t = blockIdx.x*4 + wid;
    if (t > Tz - 1) t = Tz - 1;        // clamp: duplicate work, identical output write

    __shared__ float qc[4][5][128];
    __shared__ float gqs[4][5];
    int qn = qseq[b*Sz + t + 1];
    for (int idx = lane; idx < 5*128; idx += 64) {
        int i = idx / 128, d = idx & 127;
        const float* src = (i == 0) ? (emb_q + (size_t)qn*128)
                                    : (emb_c + (size_t)qt[qn*4 + (i-1)]*128);
        qc[wid][i][d] = src[d];
    }
    __syncthreads();
    {   // gq[i] = qc[i].Ww  — per-wave butterfly
        float w0 = Ww[lane], w1 = Ww[lane + 64];
        #pragma unroll
        for (int i = 0; i < 5; ++i) {
            float p = qc[wid][i][lane]*w0 + qc[wid][i][lane+64]*w1;
            #pragma unroll
            for (int off = 32; off >= 1; off >>= 1) p += __shfl_xor(p, off);
            if (lane == 0) gqs[wid][i] = p;
        }
    }
    __syncthreads();

    const float* base = kqt + (size_t)b*(132*KTpad);

    v2f accA[5], accB[5];              // accA = (jj0,jj1), accB = (jj2,jj3)
    #pragma unroll
    for (int i = 0; i < 5; ++i) { accA[i] = (v2f){0.f,0.f}; accB[i] = (v2f){0.f,0.f}; }

    #pragma unroll 2
    for (int c = 0; c < 32; ++c) {
        float4 k0 = ((const float4*)(base + (size_t)(4*c+0)*KTpad))[lane];
        float4 k1 = ((const float4*)(base + (size_t)(4*c+1)*KTpad))[lane];
        float4 k2 = ((const float4*)(base + (size_t)(4*c+2)*KTpad))[lane];
        float4 k3 = ((const float4*)(base + (size_t)(4*c+3)*KTpad))[lane];
        v2f k0a = {k0.x,k0.y}, k0b = {k0.z,k0.w};
        v2f k1a = {k1.x,k1.y}, k1b = {k1.z,k1.w};
        v2f k2a = {k2.x,k2.y}, k2b = {k2.z,k2.w};
        v2f k3a = {k3.x,k3.y}, k3b = {k3.z,k3.w};
        #pragma unroll
        for (int i = 0; i < 5; ++i) {
            float4 q = ((const float4*)qc[wid][i])[c];       // wave-uniform b128
            v2f qa = {q.x,q.y}, qb = {q.z,q.w};
            pkfma_lo(accA[i], k0a, qa); pkfma_lo(accB[i], k0b, qa);   // d0 (q.x)
            pkfma_hi(accA[i], k1a, qa); pkfma_hi(accB[i], k1b, qa);   // d1 (q.y)
            pkfma_lo(accA[i], k2a, qb); pkfma_lo(accB[i], k2b, qb);   // d2 (q.z)
            pkfma_hi(accA[i], k3a, qb); pkfma_hi(accB[i], k3b, qb);   // d3 (q.w)
        }
    }

    const float NEG = -3.402823466e38f;
    float sv[10]; int si[10];
    #pragma unroll
    for (int k = 0; k < 10; ++k) { sv[k] = NEG; si[k] = 0x7FFFFFFF; }

    auto ins = [&](float cv, int ci) {
        if (cv > sv[9] || (cv == sv[9] && ci < si[9])) {
            #pragma unroll
            for (int k = 0; k < 10; ++k) {
                bool bet = (cv > sv[k]) || (cv == sv[k] && ci < si[k]);
                float tv = sv[k]; int ti = si[k];
                if (bet) { sv[k] = cv; si[k] = ci; cv = tv; ci = ti; }
            }
        }
    };
    {
        float4 kb4 = ((const float4*)(base + 128*KTpad))[lane];
        float kbv[4] = {kb4.x, kb4.y, kb4.z, kb4.w};
        #pragma unroll
        for (int jj = 0; jj < 4; ++jj) {
            int j = 4*lane + jj;
            if (j <= t) {
                #pragma unroll
                for (int i = 0; i < 5; ++i) {
                    float a = (jj == 0) ? accA[i].x : (jj == 1) ? accA[i].y
                            : (jj == 2) ? accB[i].x : accB[i].y;
                    ins(a + kbv[jj], i*Sz + j);
                }
            }
        }
    }

    // 10 rounds of global max (desc value, tie -> lower index), matching lax.top_k order
    float vmax = 0.f, myv = 0.f; int myidx = 0x7FFFFFFF;
    #pragma unroll
    for (int rnd = 0; rnd < 10; ++rnd) {
        float v = sv[0]; int idx = si[0];
        #pragma unroll
        for (int off = 32; off >= 1; off >>= 1) {
            float ov = __shfl_xor(v, off);
            int   oi = __shfl_xor(idx, off);
            if (ov > v || (ov == v && oi < idx)) { v = ov; idx = oi; }
        }
        if (rnd == 0) vmax = v;
        if (lane == rnd) { myv = v; myidx = idx; }
        if (si[0] == idx) {   // owner pops its head
            #pragma unroll
            for (int k = 0; k < 9; ++k) { sv[k] = sv[k+1]; si[k] = si[k+1]; }
            sv[9] = NEG; si[9] = 0x7FFFFFFF;
        }
    }

    float num = 0.f, den = 0.f;
    if (lane < 10 && myidx != 0x7FFFFFFF) {
        float a = __expf(myv - vmax);
        int ik = myidx / Sz, jk = myidx % Sz;
        float gsj = base[129*KTpad + jk];            // Ww-state dot + bw
        float f = sigm(gqs[wid][ik] + gsj);
        num = a*f; den = a;
    }
    #pragma unroll
    for (int off = 32; off >= 1; off >>= 1) {
        num += __shfl_xor(num, off);
        den += __shfl_xor(den, off);
    }
    if (lane == 0) out[b*Sz + t + 1] = num/den;
}

// ---------------- host ----------------
static inline size_t alup(size_t x) { return (x + 255) & ~(size_t)255; }

extern "C" void kernel_launch(void* const* d_in, const int* in_sizes, int n_in,
                              void* d_out, int out_size, void* d_ws, size_t ws_size,
                              hipStream_t stream) {
    (void)in_sizes; (void)n_in; (void)ws_size;
    const float* emb_q = (const float*)d_in[0];
    const float* emb_c = (const float*)d_in[1];
    const float* emb_r = (const float*)d_in[2];
    const float* Wih1  = (const float*)d_in[3];
    const float* Whh1  = (const float*)d_in[4];
    const float* bih1  = (const float*)d_in[5];
    const float* bhh1  = (const float*)d_in[6];
    const float* Wih2  = (const float*)d_in[7];
    const float* Whh2  = (const float*)d_in[8];
    const float* bih2  = (const float*)d_in[9];
    const float* bhh2  = (const float*)d_in[10];
    const float* Wg1   = (const float*)d_in[11];
    const float* Wg2   = (const float*)d_in[12];
    const float* Wg3   = (const float*)d_in[13];
    const float* Wagg  = (const float*)d_in[14];
    const float* bagg  = (const float*)d_in[15];
    const float* Wq    = (const float*)d_in[16];
    const float* bq    = (const float*)d_in[17];
    const float* Wk    = (const float*)d_in[18];
    const float* bk    = (const float*)d_in[19];
    const float* Ww    = (const float*)d_in[20];
    const float* bw    = (const float*)d_in[21];
    const int* qseq    = (const int*)d_in[22];
    const int* cseq    = (const int*)d_in[23];
    const int* mseq    = (const int*)d_in[24];
    const int* qtab    = (const int*)d_in[25];
    float* out = (float*)d_out;

    char* p = (char*)d_ws;
    auto alloc = [&](size_t bytes) { char* r = p; p += alup(bytes); return r; };
    int*   cnt    = (int*)  alloc(4096);
    int*   fill   = (int*)  alloc(4096);               // contiguous with cnt
    int*   offs   = (int*)  alloc(1001*4);
    int*   edge_q = (int*)  alloc((size_t)NEz*4);
    float* m2     = (float*)alloc((size_t)NCz*128*4);
    float* T1     = (float*)alloc(128*128*4);
    float* T2     = (float*)alloc(128*128*4);
    float* Mt     = (float*)alloc(128*128*4);
    float* gr     = (float*)alloc(2*384*4);
    float* Bkq    = (float*)alloc(132*128*4);
    float* biaskq = (float*)alloc(132*4);
    float* eq     = (float*)alloc((size_t)NSz*128*4);
    float* gi1    = (float*)alloc((size_t)NSz*384*4);
    float* stateh = (float*)alloc((size_t)NSz*128*4);
    float* kqt    = (float*)alloc((size_t)Bz*132*KTpad*4);   // transposed kq operand
    // aliases: eq is dead after the gi1 GEMM -> reuse as h1 sequence;
    //          gi1 is dead after scan1 -> reuse as gi2.
    float* h1all = eq;
    float* gi2   = gi1;

    hipMemsetAsync(cnt, 0, 8192, stream);                       // cnt + fill
    hipMemsetAsync(d_out, 0, (size_t)out_size*4, stream);       // y[:,0] = 0

    k_count<<<(NEz+255)/256, 256, 0, stream>>>(qtab, cnt);
    k_offs <<<1, 1024, 0, stream>>>(cnt, offs);
    k_fill <<<(NEz+255)/256, 256, 0, stream>>>(qtab, offs, fill, edge_q);
    k_m2   <<<NCz, 512, 0, stream>>>(qtab, offs, edge_q, emb_q, emb_c, m2);

    k_mm128<false><<<128, 128, 0, stream>>>(Wg2, Wg1, T1);      // T1 = Wg2*Wg1
    k_mm128<false><<<128, 128, 0, stream>>>(Wg3, T1, T2);       // T2 = Wg3*T1
    k_mm128<true> <<<128, 128, 0, stream>>>(Wagg, T2, Mt);      // Mt = (Wagg*T2)^T
    k_gr  <<<1, 768, 0, stream>>>(emb_r, Wih1, bih1, gr);
    k_bkq <<<130, 128, 0, stream>>>(Wq, Wk, bq, bk, Ww, bw, Bkq, biaskq);

    k_eq  <<<NSz/16, 256, 0, stream>>>(Mt, bagg, emb_q, emb_c, m2, qseq, mseq, qtab, eq);

    // gi1 = eq @ Wih1[:, :128]^T + gr[r_t]   (input gates, layer 1)  [bf16-dot2]
    k_gemm<1,1><<<dim3(NSz/64, 6), dim3(16,16), 0, stream>>>(eq, Wih1, 256, 384,
                                                             gi1, 384, nullptr, gr, cseq);
    // layer-1 scan (Whh1 only) -> h1 sequence (overwrites eq); 2 chains/block
    k_scan<<<Bz/2, 384, 0, stream>>>(gi1, Whh1, bhh1, h1all);
    // gi2 = h1 @ Wih2^T + bih2  (input gates, layer 2; overwrites gi1)  [bf16-dot2]
    k_gemm<0,1><<<dim3(NSz/64, 6), dim3(16,16), 0, stream>>>(h1all, Wih2, 128, 384,
                                                             gi2, 384, bih2, nullptr, nullptr);
    // layer-2 scan (Whh2 only) -> h2 sequence; 2 chains/block
    k_scan<<<Bz/2, 384, 0, stream>>>(gi2, Whh2, bhh2, stateh);

    // kqt: fp32 path, TRANSPOSED store (attention scores / top-k ordering untouched)
    k_gemm<2,0><<<dim3(NSz/64, 3), dim3(16,16), 0, stream>>>(stateh, Bkq, 128, 132,
                                                             kqt, 0, biaskq, nullptr, nullptr);
    k_attn<<<dim3((Tz+3)/4, Bz), 256, 0, stream>>>(kqt, qseq, qtab, emb_q, emb_c, Ww, out);
}

// Round 14
// 695.345 us; speedup vs baseline: 1.0338x; 1.0338x over previous
//
#include <hip/hip_runtime.h>
#include <math.h>

#define Bz 64
#define Sz 200
#define Dz 128
#define NQz 50000
#define NCz 1000
#define MCz 4
#define Kz 10
#define Tz 199            // S-1 scan steps
#define NSz (Bz*Tz)       // 12736 (b,t) slots; 12736/64 = 199 exactly
#define NEz (NQz*MCz)     // 200000 edges
#define KTpad 256         // padded t-dim of transposed kqt

// ---------------- GNN: CSR build + per-concept aggregation ----------------
__global__ void k_count(const int* __restrict__ qt, int* __restrict__ cnt) {
    int e = blockIdx.x*256 + threadIdx.x;
    if (e < NEz) atomicAdd(&cnt[qt[e]], 1);
}

__global__ void k_offs(const int* __restrict__ cnt, int* __restrict__ offs) {
    __shared__ int s[1024];
    int tid = threadIdx.x;
    s[tid] = (tid < NCz) ? cnt[tid] : 0;
    __syncthreads();
    for (int off = 1; off < 1024; off <<= 1) {
        int add = (tid >= off) ? s[tid - off] : 0;
        __syncthreads();
        s[tid] += add;
        __syncthreads();
    }
    if (tid < NCz) offs[tid + 1] = s[tid];
    if (tid == 0) offs[0] = 0;
}

__global__ void k_fill(const int* __restrict__ qt, const int* __restrict__ offs,
                       int* __restrict__ fill, int* __restrict__ edge_q) {
    int e = blockIdx.x*256 + threadIdx.x;
    if (e < NEz) {
        int c = qt[e];
        int pos = atomicAdd(&fill[c], 1);
        edge_q[offs[c] + pos] = e >> 2;     // question id
    }
}

// m2[c] = mean over edges (q->c) of ( emb_q[q] + 0.25*sum_m emb_c[q_table[q][m]] )
__global__ void k_m2(const int* __restrict__ qt, const int* __restrict__ offs,
                     const int* __restrict__ edge_q,
                     const float* __restrict__ emb_q, const float* __restrict__ emb_c,
                     float* __restrict__ m2) {
    int c = blockIdx.x;
    int g = threadIdx.x >> 7;      // 0..3
    int d = threadIdx.x & 127;
    int e0 = offs[c], e1 = offs[c+1];
    float acc = 0.f;
    for (int e = e0 + g; e < e1; e += 4) {
        int q = edge_q[e];
        const int* t4 = qt + q*4;
        int c0 = t4[0], c1 = t4[1], c2 = t4[2], c3 = t4[3];
        acc += emb_q[q*128 + d]
             + 0.25f*(emb_c[c0*128+d] + emb_c[c1*128+d] + emb_c[c2*128+d] + emb_c[c3*128+d]);
    }
    __shared__ float ps[4][128];
    ps[g][d] = acc;
    __syncthreads();
    if (g == 0) {
        float tot = ps[0][d] + ps[1][d] + ps[2][d] + ps[3][d];
        float cn = (float)(e1 - e0);
        m2[c*128 + d] = tot / fmaxf(cn, 1.0f);
    }
}

// ---------------- small 128x128 matmuls (weight folding) ----------------
template<bool TR>
__global__ void k_mm128(const float* __restrict__ X, const float* __restrict__ Y,
                        float* __restrict__ out) {
    int r = blockIdx.x, c = threadIdx.x;
    float acc = 0.f;
    for (int e = 0; e < 128; ++e) acc += X[r*128 + e] * Y[e*128 + c];
    if (TR) out[c*128 + r] = acc;           // store transposed (Mt[d][r] = M[r][d])
    else    out[r*128 + c] = acc;
}

// gr[rt][r] = bih1[r] + sum_e emb_r[rt][e]*Wih1[r][128+e]   (response-part of gi1, bias folded)
__global__ void k_gr(const float* __restrict__ emb_r, const float* __restrict__ Wih1,
                     const float* __restrict__ bih1, float* __restrict__ gr) {
    int rt = threadIdx.x / 384, r = threadIdx.x % 384;   // block 768
    float acc = bih1[r];
    for (int e = 0; e < 128; ++e) acc += emb_r[rt*128 + e] * Wih1[r*256 + 128 + e];
    gr[rt*384 + r] = acc;
}

// Bkq rows 0..127: G = Wq^T Wk;  row 128: wkb = Wk^T bq;  row 129: Ww[0][128:256]
// biaskq: 0..127: Wq^T bk;  128: bq.bk;  129: bw
__global__ void k_bkq(const float* __restrict__ Wq, const float* __restrict__ Wk,
                      const float* __restrict__ bq, const float* __restrict__ bk,
                      const float* __restrict__ Ww, const float* __restrict__ bw,
                      float* __restrict__ Bkq, float* __restrict__ biaskq) {
    int r = blockIdx.x, d = threadIdx.x;
    if (r < 128) {
        float acc = 0.f;
        for (int n = 0; n < 128; ++n) acc += Wq[n*128 + r] * Wk[n*128 + d];
        Bkq[r*128 + d] = acc;
        if (d == 0) {
            float b0 = 0.f;
            for (int n = 0; n < 128; ++n) b0 += Wq[n*128 + r] * bk[n];
            biaskq[r] = b0;
        }
    } else if (r == 128) {
        float acc = 0.f;
        for (int n = 0; n < 128; ++n) acc += bq[n] * Wk[n*128 + d];
        Bkq[128*128 + d] = acc;
        if (d == 0) {
            float c0 = 0.f;
            for (int n = 0; n < 128; ++n) c0 += bq[n] * bk[n];
            biaskq[128] = c0;
        }
    } else {
        Bkq[129*128 + d] = Ww[128 + d];
        if (d == 0) biaskq[129] = bw[0];
    }
}

// ---------------- per-slot GNN question embedding ----------------
__global__ void k_eq(const float* __restrict__ Mt_g, const float* __restrict__ bagg,
                     const float* __restrict__ emb_q, const float* __restrict__ emb_c,
                     const float* __restrict__ m2, const int* __restrict__ qseq,
                     const int* __restrict__ mseq, const int* __restrict__ qt,
                     float* __restrict__ eq) {
    __shared__ float Mt[128*128];
    __shared__ float ub[2][128];
    int tid = threadIdx.x;
    for (int i = tid; i < 128*128/4; i += 256)
        ((float4*)Mt)[i] = ((const float4*)Mt_g)[i];
    __syncthreads();
    int g = tid >> 7, d = tid & 127;
    for (int it = 0; it < 8; ++it) {
        int slot = blockIdx.x*16 + it*2 + g;            // grid 796 -> slots exactly cover NSz
        int b = slot / Tz, t = slot % Tz;
        int q = qseq[b*Sz + t];
        int msk = mseq[b*Sz + t];
        if (msk) {
            const int* t4 = qt + q*4;
            int c0 = t4[0], c1 = t4[1], c2 = t4[2], c3 = t4[3];
            ub[g][d] = emb_q[q*128 + d]
                     + 0.5f *(emb_c[c0*128+d] + emb_c[c1*128+d] + emb_c[c2*128+d] + emb_c[c3*128+d])
                     + 0.25f*(m2[c0*128+d]  + m2[c1*128+d]  + m2[c2*128+d]  + m2[c3*128+d]);
        }
        __syncthreads();
        if (msk) {
            float acc = bagg[d];
            const float* urow = ub[g];
            for (int e = 0; e < 128; ++e) acc += Mt[e*128 + d] * urow[e];
            eq[slot*128 + d] = tanhf(acc);
        } else {
            eq[slot*128 + d] = emb_q[q*128 + d];
        }
        __syncthreads();
    }
}

// ---------------- numeric helpers ----------------
__device__ __forceinline__ float bf_lo(unsigned u){ return __uint_as_float(u << 16); }
__device__ __forceinline__ float bf_hi(unsigned u){ return __uint_as_float(u & 0xffff0000u); }
__device__ __forceinline__ unsigned f2bf(float x){          // RNE round to bf16 (bits in low 16)
    unsigned u = __float_as_uint(x);
    return (u + 0x7fffu + ((u >> 16) & 1u)) >> 16;
}
__device__ __forceinline__ unsigned pk2(float a, float b){
    return f2bf(a) | (f2bf(b) << 16);
}
__device__ __forceinline__ float rcpf(float x){ return __builtin_amdgcn_rcpf(x); }
__device__ __forceinline__ float sigm(float x){ return rcpf(1.f + __expf(-x)); }
__device__ __forceinline__ float tanh_fast(float x){
    float e = __expf(2.f*x);
    return 1.f - 2.f*rcpf(e + 1.f);
}

#if __has_builtin(__builtin_amdgcn_fdot2_f32_bf16)
typedef __attribute__((ext_vector_type(2))) short short2v;
__device__ __forceinline__ float bdot2(unsigned w, unsigned h, float acc) {
    return __builtin_amdgcn_fdot2_f32_bf16(__builtin_bit_cast(short2v, w),
                                           __builtin_bit_cast(short2v, h), acc, false);
}
#else
__device__ __forceinline__ float bdot2(unsigned w, unsigned h, float acc) {
    return acc + bf_lo(w)*bf_lo(h) + bf_hi(w)*bf_hi(h);
}
#endif

// packed fp32 FMA (VOP3P): acc.lo += k.lo*q_sel, acc.hi += k.hi*q_sel.
typedef __attribute__((ext_vector_type(2))) float v2f;
__device__ __forceinline__ void pkfma_lo(v2f &acc, v2f k, v2f q) {   // q.lo broadcast
    asm("v_pk_fma_f32 %0, %1, %2, %0 op_sel_hi:[1,0,1]"
        : "+v"(acc) : "v"(k), "v"(q));
}
__device__ __forceinline__ void pkfma_hi(v2f &acc, v2f k, v2f q) {   // q.hi broadcast
    asm("v_pk_fma_f32 %0, %1, %2, %0 op_sel:[0,1,0] op_sel_hi:[1,1,1]"
        : "+v"(acc) : "v"(k), "v"(q));
}

// ---------------- tiled GEMM: C[s][n] = A[s][:128] . Bm[n][:128] + epilogue ----------------
// MODE 0: + bias[n] (gi2)   MODE 1: + gr[rt(s)][n] (gi1)
// MODE 2: + bias[n], store TRANSPOSED: C[(b*132+n)*KTpad + t]  (kqt path)
// DOT2 1: bf16-pair LDS staging + v_dot2 inner loop (gi GEMMs only).
template<int MODE, int DOT2>
__global__ void k_gemm(const float* __restrict__ A, const float* __restrict__ Bm,
                       int ldb, int nB, float* __restrict__ C, int ldc,
                       const float* __restrict__ bias, const float* __restrict__ gr,
                       const int* __restrict__ cseq) {
    __shared__ int rtb[64];
    int tx = threadIdx.x, ty = threadIdx.y;
    int tid = ty*16 + tx;
    int m0 = blockIdx.x * 64;
    int n0 = blockIdx.y * 64;
    if (MODE == 1 && tid < 64) {
        int s = m0 + tid;
        int b = s / Tz, t = s % Tz;
        rtb[tid] = cseq[b*Sz + t];
    }
    float acc[4][4];
    #pragma unroll
    for (int i = 0; i < 4; ++i)
        #pragma unroll
        for (int j = 0; j < 4; ++j) acc[i][j] = 0.f;

    if (DOT2) {
        __shared__ unsigned As[64][17];     // 16 bf16-pairs per row (+1 pad)
        __shared__ unsigned Bs[64][17];
        for (int kc = 0; kc < 128; kc += 32) {
            #pragma unroll
            for (int l = 0; l < 2; ++l) {
                int v = tid*2 + l;                 // 0..511
                int row = v >> 3, c4 = (v & 7) << 2;
                int p0 = (kc + c4) >> 1 & 15;      // pair index within tile
                float4 av = *(const float4*)(A + (size_t)(m0+row)*128 + kc + c4);
                As[row][p0]   = pk2(av.x, av.y);
                As[row][p0+1] = pk2(av.z, av.w);
                int nrow = n0 + row;
                float4 bv = make_float4(0.f, 0.f, 0.f, 0.f);
                if (nrow < nB) bv = *(const float4*)(Bm + (size_t)nrow*ldb + kc + c4);
                Bs[row][p0]   = pk2(bv.x, bv.y);
                Bs[row][p0+1] = pk2(bv.z, bv.w);
            }
            __syncthreads();
            #pragma unroll 4
            for (int kp = 0; kp < 16; ++kp) {
                unsigned av[4], bv[4];
                #pragma unroll
                for (int i = 0; i < 4; ++i) av[i] = As[ty*4+i][kp];
                #pragma unroll
                for (int j = 0; j < 4; ++j) bv[j] = Bs[tx*4+j][kp];
                #pragma unroll
                for (int i = 0; i < 4; ++i)
                    #pragma unroll
                    for (int j = 0; j < 4; ++j) acc[i][j] = bdot2(av[i], bv[j], acc[i][j]);
            }
            __syncthreads();
        }
    } else {
        __shared__ float Asf[64][33];
        __shared__ float Bsf[64][33];
        for (int kc = 0; kc < 128; kc += 32) {
            #pragma unroll
            for (int l = 0; l < 2; ++l) {
                int v = tid*2 + l;                 // 0..511
                int row = v >> 3, c4 = (v & 7) << 2;
                float4 av = *(const float4*)(A + (size_t)(m0+row)*128 + kc + c4);
                Asf[row][c4+0] = av.x; Asf[row][c4+1] = av.y; Asf[row][c4+2] = av.z; Asf[row][c4+3] = av.w;
                int nrow = n0 + row;
                float4 bv = make_float4(0.f, 0.f, 0.f, 0.f);
                if (nrow < nB) bv = *(const float4*)(Bm + (size_t)nrow*ldb + kc + c4);
                Bsf[row][c4+0] = bv.x; Bsf[row][c4+1] = bv.y; Bsf[row][c4+2] = bv.z; Bsf[row][c4+3] = bv.w;
            }
            __syncthreads();
            #pragma unroll 8
            for (int k = 0; k < 32; ++k) {
                float av[4], bv[4];
                #pragma unroll
                for (int i = 0; i < 4; ++i) av[i] = Asf[ty*4+i][k];
                #pragma unroll
                for (int j = 0; j < 4; ++j) bv[j] = Bsf[tx*4+j][k];
                #pragma unroll
                for (int i = 0; i < 4; ++i)
                    #pragma unroll
                    for (int j = 0; j < 4; ++j) acc[i][j] += av[i]*bv[j];
            }
            __syncthreads();
        }
    }
    #pragma unroll
    for (int i = 0; i < 4; ++i) {
        int s = m0 + ty*4 + i;
        if (MODE == 2) {
            int bb = s / Tz, tt = s - ((int)(s / Tz))*Tz;
            #pragma unroll
            for (int j = 0; j < 4; ++j) {
                int col = n0 + tx*4 + j;
                if (col < nB)
                    C[((size_t)bb*132 + col)*KTpad + tt] = acc[i][j] + bias[col];
            }
        } else {
            #pragma unroll
            for (int j = 0; j < 4; ++j) {
                int col = n0 + tx*4 + j;
                if (col < nB) {
                    float v = acc[i][j];
                    if (MODE == 0) v += bias[col];
                    else           v += gr[rtb[ty*4+i]*384 + col];
                    C[(size_t)s*ldc + col] = v;
                }
            }
        }
    }
}

// ---------------- single-layer GRU scan: unit-parallel, 1 barrier/step ----------------
// 512 threads, 1 block per batch row. Thread (wid=tid>>6, lane) owns unit u=wid*16+(lane&15),
// quarter qh=lane>>4: holds Whh rows {u,u+128,u+256} x 32-col quarter = 48 packed-bf16 regs
// (fits any cap >= 64+eps, no spill gamble). Per step: 4 uint4 LDS reads of h-quarter
// (shared by all 3 row-dots), 48 dot2, 2 intra-wave shfl_xor to combine quarters (no LDS
// round-trip, no extra barrier), then EVERY thread computes its unit's gates (3 transc.,
// spread over 8 waves; r13 did 6 transc/thread on 2 waves). h double-buffered in LDS ->
// ONE barrier/step (r13 had 2). h_old kept in-register. gi prefetched 2 steps ahead
// (covers ~900cy HBM miss; r13's 1-step prefetch could not).
__global__ void __launch_bounds__(512, 1)
k_scan(const float* __restrict__ gi, const float* __restrict__ Whh,
       const float* __restrict__ bhh, float* __restrict__ hout) {
    int b = blockIdx.x, tid = threadIdx.x;
    int wid = tid >> 6, lane = tid & 63;
    int u  = wid*16 + (lane & 15);     // unit 0..127
    int qh = lane >> 4;                // column-quarter 0..3

    unsigned wr[16], wz[16], wn[16];
    {
        const float4* r4 = (const float4*)(Whh + (size_t)u*128       + qh*32);
        const float4* z4 = (const float4*)(Whh + (size_t)(u+128)*128 + qh*32);
        const float4* n4 = (const float4*)(Whh + (size_t)(u+256)*128 + qh*32);
        #pragma unroll
        for (int k = 0; k < 8; ++k) {
            float4 a = r4[k]; wr[2*k] = pk2(a.x, a.y); wr[2*k+1] = pk2(a.z, a.w);
            float4 c = z4[k]; wz[2*k] = pk2(c.x, c.y); wz[2*k+1] = pk2(c.z, c.w);
            float4 d = n4[k]; wn[2*k] = pk2(d.x, d.y); wn[2*k+1] = pk2(d.z, d.w);
        }
    }
    float br = bhh[u], bz = bhh[u+128], bn = bhh[u+256];

    __shared__ unsigned hb[2][64];     // h as 128 bf16 halfwords, double-buffered
    if (tid < 64) { hb[0][tid] = 0u; hb[1][tid] = 0u; }
    float hold = 0.f;

    const float* gbase = gi + (size_t)(b*Tz)*384;
    // depth-2 gi prefetch: cur (t), n1 (t+1)
    float gc0 = gbase[u], gc1 = gbase[u+128], gc2 = gbase[u+256];
    float ga0 = gbase[384+u], ga1 = gbase[384+u+128], ga2 = gbase[384+u+256];
    __syncthreads();

    for (int t = 0; t < Tz; ++t) {
        float gm0 = 0.f, gm1 = 0.f, gm2 = 0.f;
        if (t + 2 < Tz) {              // issue prefetch for t+2 (2 steps of latency cover)
            const float* gp = gbase + (size_t)(t+2)*384;
            gm0 = gp[u]; gm1 = gp[u+128]; gm2 = gp[u+256];
        }
        // read own h-quarter once; reuse for all 3 row-dots
        const unsigned* hc = hb[t & 1];
        const uint4* hv = (const uint4*)(hc + qh*16);
        uint4 h0 = hv[0], h1 = hv[1], h2 = hv[2], h3 = hv[3];
        float ar, az, an;
        {
            float p0=0.f, p1=0.f;
            p0 = bdot2(wr[0],  h0.x, p0); p1 = bdot2(wr[1],  h0.y, p1);
            p0 = bdot2(wr[2],  h0.z, p0); p1 = bdot2(wr[3],  h0.w, p1);
            p0 = bdot2(wr[4],  h1.x, p0); p1 = bdot2(wr[5],  h1.y, p1);
            p0 = bdot2(wr[6],  h1.z, p0); p1 = bdot2(wr[7],  h1.w, p1);
            p0 = bdot2(wr[8],  h2.x, p0); p1 = bdot2(wr[9],  h2.y, p1);
            p0 = bdot2(wr[10], h2.z, p0); p1 = bdot2(wr[11], h2.w, p1);
            p0 = bdot2(wr[12], h3.x, p0); p1 = bdot2(wr[13], h3.y, p1);
            p0 = bdot2(wr[14], h3.z, p0); p1 = bdot2(wr[15], h3.w, p1);
            ar = p0 + p1;
        }
        {
            float p0=0.f, p1=0.f;
            p0 = bdot2(wz[0],  h0.x, p0); p1 = bdot2(wz[1],  h0.y, p1);
            p0 = bdot2(wz[2],  h0.z, p0); p1 = bdot2(wz[3],  h0.w, p1);
            p0 = bdot2(wz[4],  h1.x, p0); p1 = bdot2(wz[5],  h1.y, p1);
            p0 = bdot2(wz[6],  h1.z, p0); p1 = bdot2(wz[7],  h1.w, p1);
            p0 = bdot2(wz[8],  h2.x, p0); p1 = bdot2(wz[9],  h2.y, p1);
            p0 = bdot2(wz[10], h2.z, p0); p1 = bdot2(wz[11], h2.w, p1);
            p0 = bdot2(wz[12], h3.x, p0); p1 = bdot2(wz[13], h3.y, p1);
            p0 = bdot2(wz[14], h3.z, p0); p1 = bdot2(wz[15], h3.w, p1);
            az = p0 + p1;
        }
        {
            float p0=0.f, p1=0.f;
            p0 = bdot2(wn[0],  h0.x, p0); p1 = bdot2(wn[1],  h0.y, p1);
            p0 = bdot2(wn[2],  h0.z, p0); p1 = bdot2(wn[3],  h0.w, p1);
            p0 = bdot2(wn[4],  h1.x, p0); p1 = bdot2(wn[5],  h1.y, p1);
            p0 = bdot2(wn[6],  h1.z, p0); p1 = bdot2(wn[7],  h1.w, p1);
            p0 = bdot2(wn[8],  h2.x, p0); p1 = bdot2(wn[9],  h2.y, p1);
            p0 = bdot2(wn[10], h2.z, p0); p1 = bdot2(wn[11], h2.w, p1);
            p0 = bdot2(wn[12], h3.x, p0); p1 = bdot2(wn[13], h3.y, p1);
            p0 = bdot2(wn[14], h3.z, p0); p1 = bdot2(wn[15], h3.w, p1);
            an = p0 + p1;
        }
        // combine quarters within the wave (lanes u, u+16, u+32, u+48)
        ar += __shfl_xor(ar, 16); ar += __shfl_xor(ar, 32);
        az += __shfl_xor(az, 16); az += __shfl_xor(az, 32);
        an += __shfl_xor(an, 16); an += __shfl_xor(an, 32);
        // gates (all 4 quarter-threads redundantly; identical values)
        float rr = sigm(gc0 + br + ar);
        float zz = sigm(gc1 + bz + az);
        float nn = tanh_fast(gc2 + rr*(bn + an));
        float hnew = (1.f - zz)*nn + zz*hold;
        hold = hnew;
        if (qh == 0) {
            ((unsigned short*)hb[(t & 1) ^ 1])[u] = (unsigned short)f2bf(hnew);
            hout[(size_t)(b*Tz + t)*128 + u] = hnew;
        }
        gc0 = ga0; gc1 = ga1; gc2 = ga2;
        ga0 = gm0; ga1 = gm1; ga2 = gm2;
        __syncthreads();
    }
}

// ---------------- attention + top-k + output (kqt + packed-fp32 FMA) ----------------
__global__ void __launch_bounds__(256, 1)
k_attn(const float* __restrict__ kqt, const int* __restrict__ qseq,
       const int* __restrict__ qt, const float* __restrict__ emb_q,
       const float* __restrict__ emb_c, const float* __restrict__ Ww,
       float* __restrict__ out) {
    int wid  = threadIdx.x >> 6;
    int lane = threadIdx.x & 63;
    int b = blockIdx.y;
    int t = blockIdx.x*4 + wid;
    if (t > Tz - 1) t = Tz - 1;        // clamp: duplicate work, identical output write

    __shared__ float qc[4][5][128];
    __shared__ float gqs[4][5];
    int qn = qseq[b*Sz + t + 1];
    for (int idx = lane; idx < 5*128; idx += 64) {
        int i = idx / 128, d = idx & 127;
        const float* src = (i == 0) ? (emb_q + (size_t)qn*128)
                                    : (emb_c + (size_t)qt[qn*4 + (i-1)]*128);
        qc[wid][i][d] = src[d];
    }
    __syncthreads();
    {   // gq[i] = qc[i].Ww  — per-wave butterfly
        float w0 = Ww[lane], w1 = Ww[lane + 64];
        #pragma unroll
        for (int i = 0; i < 5; ++i) {
            float p = qc[wid][i][lane]*w0 + qc[wid][i][lane+64]*w1;
            #pragma unroll
            for (int off = 32; off >= 1; off >>= 1) p += __shfl_xor(p, off);
            if (lane == 0) gqs[wid][i] = p;
        }
    }
    __syncthreads();

    const float* base = kqt + (size_t)b*(132*KTpad);

    v2f accA[5], accB[5];              // accA = (jj0,jj1), accB = (jj2,jj3)
    #pragma unroll
    for (int i = 0; i < 5; ++i) { accA[i] = (v2f){0.f,0.f}; accB[i] = (v2f){0.f,0.f}; }

    #pragma unroll 2
    for (int c = 0; c < 32; ++c) {
        float4 k0 = ((const float4*)(base + (size_t)(4*c+0)*KTpad))[lane];
        float4 k1 = ((const float4*)(base + (size_t)(4*c+1)*KTpad))[lane];
        float4 k2 = ((const float4*)(base + (size_t)(4*c+2)*KTpad))[lane];
        float4 k3 = ((const float4*)(base + (size_t)(4*c+3)*KTpad))[lane];
        v2f k0a = {k0.x,k0.y}, k0b = {k0.z,k0.w};
        v2f k1a = {k1.x,k1.y}, k1b = {k1.z,k1.w};
        v2f k2a = {k2.x,k2.y}, k2b = {k2.z,k2.w};
        v2f k3a = {k3.x,k3.y}, k3b = {k3.z,k3.w};
        #pragma unroll
        for (int i = 0; i < 5; ++i) {
            float4 q = ((const float4*)qc[wid][i])[c];       // wave-uniform b128
            v2f qa = {q.x,q.y}, qb = {q.z,q.w};
            pkfma_lo(accA[i], k0a, qa); pkfma_lo(accB[i], k0b, qa);   // d0 (q.x)
            pkfma_hi(accA[i], k1a, qa); pkfma_hi(accB[i], k1b, qa);   // d1 (q.y)
            pkfma_lo(accA[i], k2a, qb); pkfma_lo(accB[i], k2b, qb);   // d2 (q.z)
            pkfma_hi(accA[i], k3a, qb); pkfma_hi(accB[i], k3b, qb);   // d3 (q.w)
        }
    }

    const float NEG = -3.402823466e38f;
    float sv[10]; int si[10];
    #pragma unroll
    for (int k = 0; k < 10; ++k) { sv[k] = NEG; si[k] = 0x7FFFFFFF; }

    auto ins = [&](float cv, int ci) {
        if (cv > sv[9] || (cv == sv[9] && ci < si[9])) {
            #pragma unroll
            for (int k = 0; k < 10; ++k) {
                bool bet = (cv > sv[k]) || (cv == sv[k] && ci < si[k]);
                float tv = sv[k]; int ti = si[k];
                if (bet) { sv[k] = cv; si[k] = ci; cv = tv; ci = ti; }
            }
        }
    };
    {
        float4 kb4 = ((const float4*)(base + 128*KTpad))[lane];
        float kbv[4] = {kb4.x, kb4.y, kb4.z, kb4.w};
        #pragma unroll
        for (int jj = 0; jj < 4; ++jj) {
            int j = 4*lane + jj;
            if (j <= t) {
                #pragma unroll
                for (int i = 0; i < 5; ++i) {
                    float a = (jj == 0) ? accA[i].x : (jj == 1) ? accA[i].y
                            : (jj == 2) ? accB[i].x : accB[i].y;
                    ins(a + kbv[jj], i*Sz + j);
                }
            }
        }
    }

    // 10 rounds of global max (desc value, tie -> lower index), matching lax.top_k order
    float vmax = 0.f, myv = 0.f; int myidx = 0x7FFFFFFF;
    #pragma unroll
    for (int rnd = 0; rnd < 10; ++rnd) {
        float v = sv[0]; int idx = si[0];
        #pragma unroll
        for (int off = 32; off >= 1; off >>= 1) {
            float ov = __shfl_xor(v, off);
            int   oi = __shfl_xor(idx, off);
            if (ov > v || (ov == v && oi < idx)) { v = ov; idx = oi; }
        }
        if (rnd == 0) vmax = v;
        if (lane == rnd) { myv = v; myidx = idx; }
        if (si[0] == idx) {   // owner pops its head
            #pragma unroll
            for (int k = 0; k < 9; ++k) { sv[k] = sv[k+1]; si[k] = si[k+1]; }
            sv[9] = NEG; si[9] = 0x7FFFFFFF;
        }
    }

    float num = 0.f, den = 0.f;
    if (lane < 10 && myidx != 0x7FFFFFFF) {
        float a = __expf(myv - vmax);
        int ik = myidx / Sz, jk = myidx % Sz;
        float gsj = base[129*KTpad + jk];            // Ww-state dot + bw
        float f = sigm(gqs[wid][ik] + gsj);
        num = a*f; den = a;
    }
    #pragma unroll
    for (int off = 32; off >= 1; off >>= 1) {
        num += __shfl_xor(num, off);
        den += __shfl_xor(den, off);
    }
    if (lane == 0) out[b*Sz + t + 1] = num/den;
}

// ---------------- host ----------------
static inline size_t alup(size_t x) { return (x + 255) & ~(size_t)255; }

extern "C" void kernel_launch(void* const* d_in, const int* in_sizes, int n_in,
                              void* d_out, int out_size, void* d_ws, size_t ws_size,
                              hipStream_t stream) {
    (void)in_sizes; (void)n_in; (void)ws_size;
    const float* emb_q = (const float*)d_in[0];
    const float* emb_c = (const float*)d_in[1];
    const float* emb_r = (const float*)d_in[2];
    const float* Wih1  = (const float*)d_in[3];
    const float* Whh1  = (const float*)d_in[4];
    const float* bih1  = (const float*)d_in[5];
    const float* bhh1  = (const float*)d_in[6];
    const float* Wih2  = (const float*)d_in[7];
    const float* Whh2  = (const float*)d_in[8];
    const float* bih2  = (const float*)d_in[9];
    const float* bhh2  = (const float*)d_in[10];
    const float* Wg1   = (const float*)d_in[11];
    const float* Wg2   = (const float*)d_in[12];
    const float* Wg3   = (const float*)d_in[13];
    const float* Wagg  = (const float*)d_in[14];
    const float* bagg  = (const float*)d_in[15];
    const float* Wq    = (const float*)d_in[16];
    const float* bq    = (const float*)d_in[17];
    const float* Wk    = (const float*)d_in[18];
    const float* bk    = (const float*)d_in[19];
    const float* Ww    = (const float*)d_in[20];
    const float* bw    = (const float*)d_in[21];
    const int* qseq    = (const int*)d_in[22];
    const int* cseq    = (const int*)d_in[23];
    const int* mseq    = (const int*)d_in[24];
    const int* qtab    = (const int*)d_in[25];
    float* out = (float*)d_out;

    char* p = (char*)d_ws;
    auto alloc = [&](size_t bytes) { char* r = p; p += alup(bytes); return r; };
    int*   cnt    = (int*)  alloc(4096);
    int*   fill   = (int*)  alloc(4096);               // contiguous with cnt
    int*   offs   = (int*)  alloc(1001*4);
    int*   edge_q = (int*)  alloc((size_t)NEz*4);
    float* m2     = (float*)alloc((size_t)NCz*128*4);
    float* T1     = (float*)alloc(128*128*4);
    float* T2     = (float*)alloc(128*128*4);
    float* Mt     = (float*)alloc(128*128*4);
    float* gr     = (float*)alloc(2*384*4);
    float* Bkq    = (float*)alloc(132*128*4);
    float* biaskq = (float*)alloc(132*4);
    float* eq     = (float*)alloc((size_t)NSz*128*4);
    float* gi1    = (float*)alloc((size_t)NSz*384*4);
    float* stateh = (float*)alloc((size_t)NSz*128*4);
    float* kqt    = (float*)alloc((size_t)Bz*132*KTpad*4);   // transposed kq operand
    // aliases: eq is dead after the gi1 GEMM -> reuse as h1 sequence;
    //          gi1 is dead after scan1 -> reuse as gi2.
    float* h1all = eq;
    float* gi2   = gi1;

    hipMemsetAsync(cnt, 0, 8192, stream);                       // cnt + fill
    hipMemsetAsync(d_out, 0, (size_t)out_size*4, stream);       // y[:,0] = 0

    k_count<<<(NEz+255)/256, 256, 0, stream>>>(qtab, cnt);
    k_offs <<<1, 1024, 0, stream>>>(cnt, offs);
    k_fill <<<(NEz+255)/256, 256, 0, stream>>>(qtab, offs, fill, edge_q);
    k_m2   <<<NCz, 512, 0, stream>>>(qtab, offs, edge_q, emb_q, emb_c, m2);

    k_mm128<false><<<128, 128, 0, stream>>>(Wg2, Wg1, T1);      // T1 = Wg2*Wg1
    k_mm128<false><<<128, 128, 0, stream>>>(Wg3, T1, T2);       // T2 = Wg3*T1
    k_mm128<true> <<<128, 128, 0, stream>>>(Wagg, T2, Mt);      // Mt = (Wagg*T2)^T
    k_gr  <<<1, 768, 0, stream>>>(emb_r, Wih1, bih1, gr);
    k_bkq <<<130, 128, 0, stream>>>(Wq, Wk, bq, bk, Ww, bw, Bkq, biaskq);

    k_eq  <<<NSz/16, 256, 0, stream>>>(Mt, bagg, emb_q, emb_c, m2, qseq, mseq, qtab, eq);

    // gi1 = eq @ Wih1[:, :128]^T + gr[r_t]   (input gates, layer 1)  [bf16-dot2]
    k_gemm<1,1><<<dim3(NSz/64, 6), dim3(16,16), 0, stream>>>(eq, Wih1, 256, 384,
                                                             gi1, 384, nullptr, gr, cseq);
    // layer-1 scan (Whh1 only) -> h1 sequence (overwrites eq)
    k_scan<<<Bz, 512, 0, stream>>>(gi1, Whh1, bhh1, h1all);
    // gi2 = h1 @ Wih2^T + bih2  (input gates, layer 2; overwrites gi1)  [bf16-dot2]
    k_gemm<0,1><<<dim3(NSz/64, 6), dim3(16,16), 0, stream>>>(h1all, Wih2, 128, 384,
                                                             gi2, 384, bih2, nullptr, nullptr);
    // layer-2 scan (Whh2 only) -> h2 sequence
    k_scan<<<Bz, 512, 0, stream>>>(gi2, Whh2, bhh2, stateh);

    // kqt: fp32 path, TRANSPOSED store (attention scores / top-k ordering untouched)
    k_gemm<2,0><<<dim3(NSz/64, 3), dim3(16,16), 0, stream>>>(stateh, Bkq, 128, 132,
                                                             kqt, 0, biaskq, nullptr, nullptr);
    k_attn<<<dim3((Tz+3)/4, Bz), 256, 0, stream>>>(kqt, qseq, qtab, emb_q, emb_c, Ww, out);
}

// Round 15
// 668.763 us; speedup vs baseline: 1.0749x; 1.0397x over previous
//
#include <hip/hip_runtime.h>
#include <math.h>

#define Bz 64
#define Sz 200
#define Dz 128
#define NQz 50000
#define NCz 1000
#define MCz 4
#define Kz 10
#define Tz 199            // S-1 scan steps
#define NSz (Bz*Tz)       // 12736 (b,t) slots; 12736/64 = 199 exactly
#define NEz (NQz*MCz)     // 200000 edges
#define KTpad 256         // padded t-dim of transposed kqt
#define CHz 8             // gi staging chunk (steps per LDS buffer)

// ---------------- GNN: CSR build + per-concept aggregation ----------------
__global__ void k_count(const int* __restrict__ qt, int* __restrict__ cnt) {
    int e = blockIdx.x*256 + threadIdx.x;
    if (e < NEz) atomicAdd(&cnt[qt[e]], 1);
}

__global__ void k_offs(const int* __restrict__ cnt, int* __restrict__ offs) {
    __shared__ int s[1024];
    int tid = threadIdx.x;
    s[tid] = (tid < NCz) ? cnt[tid] : 0;
    __syncthreads();
    for (int off = 1; off < 1024; off <<= 1) {
        int add = (tid >= off) ? s[tid - off] : 0;
        __syncthreads();
        s[tid] += add;
        __syncthreads();
    }
    if (tid < NCz) offs[tid + 1] = s[tid];
    if (tid == 0) offs[0] = 0;
}

__global__ void k_fill(const int* __restrict__ qt, const int* __restrict__ offs,
                       int* __restrict__ fill, int* __restrict__ edge_q) {
    int e = blockIdx.x*256 + threadIdx.x;
    if (e < NEz) {
        int c = qt[e];
        int pos = atomicAdd(&fill[c], 1);
        edge_q[offs[c] + pos] = e >> 2;     // question id
    }
}

// m2[c] = mean over edges (q->c) of ( emb_q[q] + 0.25*sum_m emb_c[q_table[q][m]] )
__global__ void k_m2(const int* __restrict__ qt, const int* __restrict__ offs,
                     const int* __restrict__ edge_q,
                     const float* __restrict__ emb_q, const float* __restrict__ emb_c,
                     float* __restrict__ m2) {
    int c = blockIdx.x;
    int g = threadIdx.x >> 7;      // 0..3
    int d = threadIdx.x & 127;
    int e0 = offs[c], e1 = offs[c+1];
    float acc = 0.f;
    for (int e = e0 + g; e < e1; e += 4) {
        int q = edge_q[e];
        const int* t4 = qt + q*4;
        int c0 = t4[0], c1 = t4[1], c2 = t4[2], c3 = t4[3];
        acc += emb_q[q*128 + d]
             + 0.25f*(emb_c[c0*128+d] + emb_c[c1*128+d] + emb_c[c2*128+d] + emb_c[c3*128+d]);
    }
    __shared__ float ps[4][128];
    ps[g][d] = acc;
    __syncthreads();
    if (g == 0) {
        float tot = ps[0][d] + ps[1][d] + ps[2][d] + ps[3][d];
        float cn = (float)(e1 - e0);
        m2[c*128 + d] = tot / fmaxf(cn, 1.0f);
    }
}

// ---------------- small 128x128 matmuls (weight folding) ----------------
template<bool TR>
__global__ void k_mm128(const float* __restrict__ X, const float* __restrict__ Y,
                        float* __restrict__ out) {
    int r = blockIdx.x, c = threadIdx.x;
    float acc = 0.f;
    for (int e = 0; e < 128; ++e) acc += X[r*128 + e] * Y[e*128 + c];
    if (TR) out[c*128 + r] = acc;           // store transposed (Mt[d][r] = M[r][d])
    else    out[r*128 + c] = acc;
}

// gr[rt][r] = bih1[r] + sum_e emb_r[rt][e]*Wih1[r][128+e]   (response-part of gi1, bias folded)
__global__ void k_gr(const float* __restrict__ emb_r, const float* __restrict__ Wih1,
                     const float* __restrict__ bih1, float* __restrict__ gr) {
    int rt = threadIdx.x / 384, r = threadIdx.x % 384;   // block 768
    float acc = bih1[r];
    for (int e = 0; e < 128; ++e) acc += emb_r[rt*128 + e] * Wih1[r*256 + 128 + e];
    gr[rt*384 + r] = acc;
}

// Bkq rows 0..127: G = Wq^T Wk;  row 128: wkb = Wk^T bq;  row 129: Ww[0][128:256]
// biaskq: 0..127: Wq^T bk;  128: bq.bk;  129: bw
__global__ void k_bkq(const float* __restrict__ Wq, const float* __restrict__ Wk,
                      const float* __restrict__ bq, const float* __restrict__ bk,
                      const float* __restrict__ Ww, const float* __restrict__ bw,
                      float* __restrict__ Bkq, float* __restrict__ biaskq) {
    int r = blockIdx.x, d = threadIdx.x;
    if (r < 128) {
        float acc = 0.f;
        for (int n = 0; n < 128; ++n) acc += Wq[n*128 + r] * Wk[n*128 + d];
        Bkq[r*128 + d] = acc;
        if (d == 0) {
            float b0 = 0.f;
            for (int n = 0; n < 128; ++n) b0 += Wq[n*128 + r] * bk[n];
            biaskq[r] = b0;
        }
    } else if (r == 128) {
        float acc = 0.f;
        for (int n = 0; n < 128; ++n) acc += bq[n] * Wk[n*128 + d];
        Bkq[128*128 + d] = acc;
        if (d == 0) {
            float c0 = 0.f;
            for (int n = 0; n < 128; ++n) c0 += bq[n] * bk[n];
            biaskq[128] = c0;
        }
    } else {
        Bkq[129*128 + d] = Ww[128 + d];
        if (d == 0) biaskq[129] = bw[0];
    }
}

// ---------------- per-slot GNN question embedding ----------------
__global__ void k_eq(const float* __restrict__ Mt_g, const float* __restrict__ bagg,
                     const float* __restrict__ emb_q, const float* __restrict__ emb_c,
                     const float* __restrict__ m2, const int* __restrict__ qseq,
                     const int* __restrict__ mseq, const int* __restrict__ qt,
                     float* __restrict__ eq) {
    __shared__ float Mt[128*128];
    __shared__ float ub[2][128];
    int tid = threadIdx.x;
    for (int i = tid; i < 128*128/4; i += 256)
        ((float4*)Mt)[i] = ((const float4*)Mt_g)[i];
    __syncthreads();
    int g = tid >> 7, d = tid & 127;
    for (int it = 0; it < 8; ++it) {
        int slot = blockIdx.x*16 + it*2 + g;            // grid 796 -> slots exactly cover NSz
        int b = slot / Tz, t = slot % Tz;
        int q = qseq[b*Sz + t];
        int msk = mseq[b*Sz + t];
        if (msk) {
            const int* t4 = qt + q*4;
            int c0 = t4[0], c1 = t4[1], c2 = t4[2], c3 = t4[3];
            ub[g][d] = emb_q[q*128 + d]
                     + 0.5f *(emb_c[c0*128+d] + emb_c[c1*128+d] + emb_c[c2*128+d] + emb_c[c3*128+d])
                     + 0.25f*(m2[c0*128+d]  + m2[c1*128+d]  + m2[c2*128+d]  + m2[c3*128+d]);
        }
        __syncthreads();
        if (msk) {
            float acc = bagg[d];
            const float* urow = ub[g];
            for (int e = 0; e < 128; ++e) acc += Mt[e*128 + d] * urow[e];
            eq[slot*128 + d] = tanhf(acc);
        } else {
            eq[slot*128 + d] = emb_q[q*128 + d];
        }
        __syncthreads();
    }
}

// ---------------- numeric helpers ----------------
__device__ __forceinline__ float bf_lo(unsigned u){ return __uint_as_float(u << 16); }
__device__ __forceinline__ float bf_hi(unsigned u){ return __uint_as_float(u & 0xffff0000u); }
__device__ __forceinline__ unsigned f2bf(float x){          // RNE round to bf16 (bits in low 16)
    unsigned u = __float_as_uint(x);
    return (u + 0x7fffu + ((u >> 16) & 1u)) >> 16;
}
__device__ __forceinline__ unsigned pk2(float a, float b){
    return f2bf(a) | (f2bf(b) << 16);
}
__device__ __forceinline__ float rcpf(float x){ return __builtin_amdgcn_rcpf(x); }
__device__ __forceinline__ float sigm(float x){ return rcpf(1.f + __expf(-x)); }
__device__ __forceinline__ float tanh_fast(float x){
    float e = __expf(2.f*x);
    return 1.f - 2.f*rcpf(e + 1.f);
}

#if __has_builtin(__builtin_amdgcn_fdot2_f32_bf16)
typedef __attribute__((ext_vector_type(2))) short short2v;
__device__ __forceinline__ float bdot2(unsigned w, unsigned h, float acc) {
    return __builtin_amdgcn_fdot2_f32_bf16(__builtin_bit_cast(short2v, w),
                                           __builtin_bit_cast(short2v, h), acc, false);
}
#else
__device__ __forceinline__ float bdot2(unsigned w, unsigned h, float acc) {
    return acc + bf_lo(w)*bf_lo(h) + bf_hi(w)*bf_hi(h);
}
#endif

// packed fp32 FMA (VOP3P): acc.lo += k.lo*q_sel, acc.hi += k.hi*q_sel.
typedef __attribute__((ext_vector_type(2))) float v2f;
__device__ __forceinline__ void pkfma_lo(v2f &acc, v2f k, v2f q) {   // q.lo broadcast
    asm("v_pk_fma_f32 %0, %1, %2, %0 op_sel_hi:[1,0,1]"
        : "+v"(acc) : "v"(k), "v"(q));
}
__device__ __forceinline__ void pkfma_hi(v2f &acc, v2f k, v2f q) {   // q.hi broadcast
    asm("v_pk_fma_f32 %0, %1, %2, %0 op_sel:[0,1,0] op_sel_hi:[1,1,1]"
        : "+v"(acc) : "v"(k), "v"(q));
}

// ---------------- tiled GEMM: C[s][n] = A[s][:128] . Bm[n][:128] + epilogue ----------------
// MODE 0: + bias[n] (gi2)   MODE 1: + gr[rt(s)][n] (gi1)
// MODE 2: + bias[n], store TRANSPOSED: C[(b*132+n)*KTpad + t]  (kqt path)
// DOT2 1: bf16-pair LDS staging + v_dot2 inner loop (gi GEMMs only).
template<int MODE, int DOT2>
__global__ void k_gemm(const float* __restrict__ A, const float* __restrict__ Bm,
                       int ldb, int nB, float* __restrict__ C, int ldc,
                       const float* __restrict__ bias, const float* __restrict__ gr,
                       const int* __restrict__ cseq) {
    __shared__ int rtb[64];
    int tx = threadIdx.x, ty = threadIdx.y;
    int tid = ty*16 + tx;
    int m0 = blockIdx.x * 64;
    int n0 = blockIdx.y * 64;
    if (MODE == 1 && tid < 64) {
        int s = m0 + tid;
        int b = s / Tz, t = s % Tz;
        rtb[tid] = cseq[b*Sz + t];
    }
    float acc[4][4];
    #pragma unroll
    for (int i = 0; i < 4; ++i)
        #pragma unroll
        for (int j = 0; j < 4; ++j) acc[i][j] = 0.f;

    if (DOT2) {
        __shared__ unsigned As[64][17];     // 16 bf16-pairs per row (+1 pad)
        __shared__ unsigned Bs[64][17];
        for (int kc = 0; kc < 128; kc += 32) {
            #pragma unroll
            for (int l = 0; l < 2; ++l) {
                int v = tid*2 + l;                 // 0..511
                int row = v >> 3, c4 = (v & 7) << 2;
                int p0 = (kc + c4) >> 1 & 15;      // pair index within tile
                float4 av = *(const float4*)(A + (size_t)(m0+row)*128 + kc + c4);
                As[row][p0]   = pk2(av.x, av.y);
                As[row][p0+1] = pk2(av.z, av.w);
                int nrow = n0 + row;
                float4 bv = make_float4(0.f, 0.f, 0.f, 0.f);
                if (nrow < nB) bv = *(const float4*)(Bm + (size_t)nrow*ldb + kc + c4);
                Bs[row][p0]   = pk2(bv.x, bv.y);
                Bs[row][p0+1] = pk2(bv.z, bv.w);
            }
            __syncthreads();
            #pragma unroll 4
            for (int kp = 0; kp < 16; ++kp) {
                unsigned av[4], bv[4];
                #pragma unroll
                for (int i = 0; i < 4; ++i) av[i] = As[ty*4+i][kp];
                #pragma unroll
                for (int j = 0; j < 4; ++j) bv[j] = Bs[tx*4+j][kp];
                #pragma unroll
                for (int i = 0; i < 4; ++i)
                    #pragma unroll
                    for (int j = 0; j < 4; ++j) acc[i][j] = bdot2(av[i], bv[j], acc[i][j]);
            }
            __syncthreads();
        }
    } else {
        __shared__ float Asf[64][33];
        __shared__ float Bsf[64][33];
        for (int kc = 0; kc < 128; kc += 32) {
            #pragma unroll
            for (int l = 0; l < 2; ++l) {
                int v = tid*2 + l;                 // 0..511
                int row = v >> 3, c4 = (v & 7) << 2;
                float4 av = *(const float4*)(A + (size_t)(m0+row)*128 + kc + c4);
                Asf[row][c4+0] = av.x; Asf[row][c4+1] = av.y; Asf[row][c4+2] = av.z; Asf[row][c4+3] = av.w;
                int nrow = n0 + row;
                float4 bv = make_float4(0.f, 0.f, 0.f, 0.f);
                if (nrow < nB) bv = *(const float4*)(Bm + (size_t)nrow*ldb + kc + c4);
                Bsf[row][c4+0] = bv.x; Bsf[row][c4+1] = bv.y; Bsf[row][c4+2] = bv.z; Bsf[row][c4+3] = bv.w;
            }
            __syncthreads();
            #pragma unroll 8
            for (int k = 0; k < 32; ++k) {
                float av[4], bv[4];
                #pragma unroll
                for (int i = 0; i < 4; ++i) av[i] = Asf[ty*4+i][k];
                #pragma unroll
                for (int j = 0; j < 4; ++j) bv[j] = Bsf[tx*4+j][k];
                #pragma unroll
                for (int i = 0; i < 4; ++i)
                    #pragma unroll
                    for (int j = 0; j < 4; ++j) acc[i][j] += av[i]*bv[j];
            }
            __syncthreads();
        }
    }
    #pragma unroll
    for (int i = 0; i < 4; ++i) {
        int s = m0 + ty*4 + i;
        if (MODE == 2) {
            int bb = s / Tz, tt = s - ((int)(s / Tz))*Tz;
            #pragma unroll
            for (int j = 0; j < 4; ++j) {
                int col = n0 + tx*4 + j;
                if (col < nB)
                    C[((size_t)bb*132 + col)*KTpad + tt] = acc[i][j] + bias[col];
            }
        } else {
            #pragma unroll
            for (int j = 0; j < 4; ++j) {
                int col = n0 + tx*4 + j;
                if (col < nB) {
                    float v = acc[i][j];
                    if (MODE == 0) v += bias[col];
                    else           v += gr[rtb[ty*4+i]*384 + col];
                    C[(size_t)s*ldc + col] = v;
                }
            }
        }
    }
}

// ---------------- single-layer GRU scan: unit-parallel + LDS gi staging ----------------
// r14 post-mortem: three structures all ~140us -> shared bottleneck was the per-step gi
// global load whose register-rotation forced an in-step vmcnt wait (~900cy HBM latency).
// Fix: stage gi in 8-step LDS chunks, double-buffered. Next chunk's loads are issued at
// chunk start (6 coalesced floats/thread) and only waited on at the chunk-end ds_write —
// 8 steps (~3200cy) of compute cover the latency. Per-step gi = 3 conflict-free ds_read.
// Rest identical to r14: unit-parallel (u=wid*16+(lane&15), quarter qh=lane>>4), 48
// packed-bf16 weight regs, shfl quarter-combine, 1 barrier/step, h double-buffered.
__global__ void __launch_bounds__(512, 1)
k_scan(const float* __restrict__ gi, const float* __restrict__ Whh,
       const float* __restrict__ bhh, float* __restrict__ hout) {
    int b = blockIdx.x, tid = threadIdx.x;
    int wid = tid >> 6, lane = tid & 63;
    int u  = wid*16 + (lane & 15);     // unit 0..127
    int qh = lane >> 4;                // column-quarter 0..3

    unsigned wr[16], wz[16], wn[16];
    {
        const float4* r4 = (const float4*)(Whh + (size_t)u*128       + qh*32);
        const float4* z4 = (const float4*)(Whh + (size_t)(u+128)*128 + qh*32);
        const float4* n4 = (const float4*)(Whh + (size_t)(u+256)*128 + qh*32);
        #pragma unroll
        for (int k = 0; k < 8; ++k) {
            float4 a = r4[k]; wr[2*k] = pk2(a.x, a.y); wr[2*k+1] = pk2(a.z, a.w);
            float4 c = z4[k]; wz[2*k] = pk2(c.x, c.y); wz[2*k+1] = pk2(c.z, c.w);
            float4 d = n4[k]; wn[2*k] = pk2(d.x, d.y); wn[2*k+1] = pk2(d.z, d.w);
        }
    }
    float br = bhh[u], bz = bhh[u+128], bn = bhh[u+256];

    __shared__ unsigned hb[2][64];        // h as 128 bf16 halfwords, double-buffered
    __shared__ float gis[2][CHz][384];    // gi staging, double-buffered (24.6 KB)
    if (tid < 64) { hb[0][tid] = 0u; hb[1][tid] = 0u; }
    float hold = 0.f;

    const float* gbase = gi + (size_t)(b*Tz)*384;
    {   // prologue: stage chunk 0
        #pragma unroll
        for (int k = 0; k < 6; ++k) {
            int f = tid + k*512;               // 0..3071 over [CHz][384]
            int s = f / 384, d = f - s*384;
            int tt = s; if (tt > Tz-1) tt = Tz-1;
            gis[0][s][d] = gbase[(size_t)tt*384 + d];
        }
    }
    __syncthreads();

    const int nch = (Tz + CHz - 1) / CHz;     // 25
    for (int c = 0; c < nch; ++c) {
        float stg0=0.f, stg1=0.f, stg2=0.f, stg3=0.f, stg4=0.f, stg5=0.f;
        if (c + 1 < nch) {                    // issue next chunk's loads (wait deferred)
            #pragma unroll
            for (int k = 0; k < 6; ++k) {
                int f = tid + k*512;
                int s = f / 384, d = f - s*384;
                int tt = (c+1)*CHz + s; if (tt > Tz-1) tt = Tz-1;
                float v = gbase[(size_t)tt*384 + d];
                if (k==0) stg0=v; else if (k==1) stg1=v; else if (k==2) stg2=v;
                else if (k==3) stg3=v; else if (k==4) stg4=v; else stg5=v;
            }
        }
        int smax = Tz - c*CHz; if (smax > CHz) smax = CHz;
        for (int s = 0; s < smax; ++s) {
            int t = c*CHz + s;
            const float* grow = gis[c & 1][s];
            float gc0 = grow[u], gc1 = grow[u+128], gc2 = grow[u+256];
            // read own h-quarter once; reuse for all 3 row-dots
            const unsigned* hc = hb[t & 1];
            const uint4* hv = (const uint4*)(hc + qh*16);
            uint4 h0 = hv[0], h1 = hv[1], h2 = hv[2], h3 = hv[3];
            float ar, az, an;
            {
                float p0=0.f, p1=0.f;
                p0 = bdot2(wr[0],  h0.x, p0); p1 = bdot2(wr[1],  h0.y, p1);
                p0 = bdot2(wr[2],  h0.z, p0); p1 = bdot2(wr[3],  h0.w, p1);
                p0 = bdot2(wr[4],  h1.x, p0); p1 = bdot2(wr[5],  h1.y, p1);
                p0 = bdot2(wr[6],  h1.z, p0); p1 = bdot2(wr[7],  h1.w, p1);
                p0 = bdot2(wr[8],  h2.x, p0); p1 = bdot2(wr[9],  h2.y, p1);
                p0 = bdot2(wr[10], h2.z, p0); p1 = bdot2(wr[11], h2.w, p1);
                p0 = bdot2(wr[12], h3.x, p0); p1 = bdot2(wr[13], h3.y, p1);
                p0 = bdot2(wr[14], h3.z, p0); p1 = bdot2(wr[15], h3.w, p1);
                ar = p0 + p1;
            }
            {
                float p0=0.f, p1=0.f;
                p0 = bdot2(wz[0],  h0.x, p0); p1 = bdot2(wz[1],  h0.y, p1);
                p0 = bdot2(wz[2],  h0.z, p0); p1 = bdot2(wz[3],  h0.w, p1);
                p0 = bdot2(wz[4],  h1.x, p0); p1 = bdot2(wz[5],  h1.y, p1);
                p0 = bdot2(wz[6],  h1.z, p0); p1 = bdot2(wz[7],  h1.w, p1);
                p0 = bdot2(wz[8],  h2.x, p0); p1 = bdot2(wz[9],  h2.y, p1);
                p0 = bdot2(wz[10], h2.z, p0); p1 = bdot2(wz[11], h2.w, p1);
                p0 = bdot2(wz[12], h3.x, p0); p1 = bdot2(wz[13], h3.y, p1);
                p0 = bdot2(wz[14], h3.z, p0); p1 = bdot2(wz[15], h3.w, p1);
                az = p0 + p1;
            }
            {
                float p0=0.f, p1=0.f;
                p0 = bdot2(wn[0],  h0.x, p0); p1 = bdot2(wn[1],  h0.y, p1);
                p0 = bdot2(wn[2],  h0.z, p0); p1 = bdot2(wn[3],  h0.w, p1);
                p0 = bdot2(wn[4],  h1.x, p0); p1 = bdot2(wn[5],  h1.y, p1);
                p0 = bdot2(wn[6],  h1.z, p0); p1 = bdot2(wn[7],  h1.w, p1);
                p0 = bdot2(wn[8],  h2.x, p0); p1 = bdot2(wn[9],  h2.y, p1);
                p0 = bdot2(wn[10], h2.z, p0); p1 = bdot2(wn[11], h2.w, p1);
                p0 = bdot2(wn[12], h3.x, p0); p1 = bdot2(wn[13], h3.y, p1);
                p0 = bdot2(wn[14], h3.z, p0); p1 = bdot2(wn[15], h3.w, p1);
                an = p0 + p1;
            }
            // combine quarters within the wave (lanes u, u+16, u+32, u+48)
            ar += __shfl_xor(ar, 16); ar += __shfl_xor(ar, 32);
            az += __shfl_xor(az, 16); az += __shfl_xor(az, 32);
            an += __shfl_xor(an, 16); an += __shfl_xor(an, 32);
            // gates (all 4 quarter-threads redundantly; identical values)
            float rr = sigm(gc0 + br + ar);
            float zz = sigm(gc1 + bz + az);
            float nn = tanh_fast(gc2 + rr*(bn + an));
            float hnew = (1.f - zz)*nn + zz*hold;
            hold = hnew;
            if (qh == 0) {
                ((unsigned short*)hb[(t & 1) ^ 1])[u] = (unsigned short)f2bf(hnew);
                hout[(size_t)(b*Tz + t)*128 + u] = hnew;
            }
            __syncthreads();
        }
        if (c + 1 < nch) {                    // commit staged gi (vmcnt wait lands here)
            float stg[6] = {stg0, stg1, stg2, stg3, stg4, stg5};
            #pragma unroll
            for (int k = 0; k < 6; ++k) {
                int f = tid + k*512;
                int s = f / 384, d = f - s*384;
                gis[(c+1) & 1][s][d] = stg[k];
            }
            __syncthreads();
        }
    }
}

// ---------------- attention + top-k + output (kqt + packed-fp32 FMA) ----------------
__global__ void __launch_bounds__(256, 1)
k_attn(const float* __restrict__ kqt, const int* __restrict__ qseq,
       const int* __restrict__ qt, const float* __restrict__ emb_q,
       const float* __restrict__ emb_c, const float* __restrict__ Ww,
       float* __restrict__ out) {
    int wid  = threadIdx.x >> 6;
    int lane = threadIdx.x & 63;
    int b = blockIdx.y;
    int t = blockIdx.x*4 + wid;
    if (t > Tz - 1) t = Tz - 1;        // clamp: duplicate work, identical output write

    __shared__ float qc[4][5][128];
    __shared__ float gqs[4][5];
    int qn = qseq[b*Sz + t + 1];
    for (int idx = lane; idx < 5*128; idx += 64) {
        int i = idx / 128, d = idx & 127;
        const float* src = (i == 0) ? (emb_q + (size_t)qn*128)
                                    : (emb_c + (size_t)qt[qn*4 + (i-1)]*128);
        qc[wid][i][d] = src[d];
    }
    __syncthreads();
    {   // gq[i] = qc[i].Ww  — per-wave butterfly
        float w0 = Ww[lane], w1 = Ww[lane + 64];
        #pragma unroll
        for (int i = 0; i < 5; ++i) {
            float p = qc[wid][i][lane]*w0 + qc[wid][i][lane+64]*w1;
            #pragma unroll
            for (int off = 32; off >= 1; off >>= 1) p += __shfl_xor(p, off);
            if (lane == 0) gqs[wid][i] = p;
        }
    }
    __syncthreads();

    const float* base = kqt + (size_t)b*(132*KTpad);

    v2f accA[5], accB[5];              // accA = (jj0,jj1), accB = (jj2,jj3)
    #pragma unroll
    for (int i = 0; i < 5; ++i) { accA[i] = (v2f){0.f,0.f}; accB[i] = (v2f){0.f,0.f}; }

    #pragma unroll 2
    for (int c = 0; c < 32; ++c) {
        float4 k0 = ((const float4*)(base + (size_t)(4*c+0)*KTpad))[lane];
        float4 k1 = ((const float4*)(base + (size_t)(4*c+1)*KTpad))[lane];
        float4 k2 = ((const float4*)(base + (size_t)(4*c+2)*KTpad))[lane];
        float4 k3 = ((const float4*)(base + (size_t)(4*c+3)*KTpad))[lane];
        v2f k0a = {k0.x,k0.y}, k0b = {k0.z,k0.w};
        v2f k1a = {k1.x,k1.y}, k1b = {k1.z,k1.w};
        v2f k2a = {k2.x,k2.y}, k2b = {k2.z,k2.w};
        v2f k3a = {k3.x,k3.y}, k3b = {k3.z,k3.w};
        #pragma unroll
        for (int i = 0; i < 5; ++i) {
            float4 q = ((const float4*)qc[wid][i])[c];       // wave-uniform b128
            v2f qa = {q.x,q.y}, qb = {q.z,q.w};
            pkfma_lo(accA[i], k0a, qa); pkfma_lo(accB[i], k0b, qa);   // d0 (q.x)
            pkfma_hi(accA[i], k1a, qa); pkfma_hi(accB[i], k1b, qa);   // d1 (q.y)
            pkfma_lo(accA[i], k2a, qb); pkfma_lo(accB[i], k2b, qb);   // d2 (q.z)
            pkfma_hi(accA[i], k3a, qb); pkfma_hi(accB[i], k3b, qb);   // d3 (q.w)
        }
    }

    const float NEG = -3.402823466e38f;
    float sv[10]; int si[10];
    #pragma unroll
    for (int k = 0; k < 10; ++k) { sv[k] = NEG; si[k] = 0x7FFFFFFF; }

    auto ins = [&](float cv, int ci) {
        if (cv > sv[9] || (cv == sv[9] && ci < si[9])) {
            #pragma unroll
            for (int k = 0; k < 10; ++k) {
                bool bet = (cv > sv[k]) || (cv == sv[k] && ci < si[k]);
                float tv = sv[k]; int ti = si[k];
                if (bet) { sv[k] = cv; si[k] = ci; cv = tv; ci = ti; }
            }
        }
    };
    {
        float4 kb4 = ((const float4*)(base + 128*KTpad))[lane];
        float kbv[4] = {kb4.x, kb4.y, kb4.z, kb4.w};
        #pragma unroll
        for (int jj = 0; jj < 4; ++jj) {
            int j = 4*lane + jj;
            if (j <= t) {
                #pragma unroll
                for (int i = 0; i < 5; ++i) {
                    float a = (jj == 0) ? accA[i].x : (jj == 1) ? accA[i].y
                            : (jj == 2) ? accB[i].x : accB[i].y;
                    ins(a + kbv[jj], i*Sz + j);
                }
            }
        }
    }

    // 10 rounds of global max (desc value, tie -> lower index), matching lax.top_k order
    float vmax = 0.f, myv = 0.f; int myidx = 0x7FFFFFFF;
    #pragma unroll
    for (int rnd = 0; rnd < 10; ++rnd) {
        float v = sv[0]; int idx = si[0];
        #pragma unroll
        for (int off = 32; off >= 1; off >>= 1) {
            float ov = __shfl_xor(v, off);
            int   oi = __shfl_xor(idx, off);
            if (ov > v || (ov == v && oi < idx)) { v = ov; idx = oi; }
        }
        if (rnd == 0) vmax = v;
        if (lane == rnd) { myv = v; myidx = idx; }
        if (si[0] == idx) {   // owner pops its head
            #pragma unroll
            for (int k = 0; k < 9; ++k) { sv[k] = sv[k+1]; si[k] = si[k+1]; }
            sv[9] = NEG; si[9] = 0x7FFFFFFF;
        }
    }

    float num = 0.f, den = 0.f;
    if (lane < 10 && myidx != 0x7FFFFFFF) {
        float a = __expf(myv - vmax);
        int ik = myidx / Sz, jk = myidx % Sz;
        float gsj = base[129*KTpad + jk];            // Ww-state dot + bw
        float f = sigm(gqs[wid][ik] + gsj);
        num = a*f; den = a;
    }
    #pragma unroll
    for (int off = 32; off >= 1; off >>= 1) {
        num += __shfl_xor(num, off);
        den += __shfl_xor(den, off);
    }
    if (lane == 0) out[b*Sz + t + 1] = num/den;
}

// ---------------- host ----------------
static inline size_t alup(size_t x) { return (x + 255) & ~(size_t)255; }

extern "C" void kernel_launch(void* const* d_in, const int* in_sizes, int n_in,
                              void* d_out, int out_size, void* d_ws, size_t ws_size,
                              hipStream_t stream) {
    (void)in_sizes; (void)n_in; (void)ws_size;
    const float* emb_q = (const float*)d_in[0];
    const float* emb_c = (const float*)d_in[1];
    const float* emb_r = (const float*)d_in[2];
    const float* Wih1  = (const float*)d_in[3];
    const float* Whh1  = (const float*)d_in[4];
    const float* bih1  = (const float*)d_in[5];
    const float* bhh1  = (const float*)d_in[6];
    const float* Wih2  = (const float*)d_in[7];
    const float* Whh2  = (const float*)d_in[8];
    const float* bih2  = (const float*)d_in[9];
    const float* bhh2  = (const float*)d_in[10];
    const float* Wg1   = (const float*)d_in[11];
    const float* Wg2   = (const float*)d_in[12];
    const float* Wg3   = (const float*)d_in[13];
    const float* Wagg  = (const float*)d_in[14];
    const float* bagg  = (const float*)d_in[15];
    const float* Wq    = (const float*)d_in[16];
    const float* bq    = (const float*)d_in[17];
    const float* Wk    = (const float*)d_in[18];
    const float* bk    = (const float*)d_in[19];
    const float* Ww    = (const float*)d_in[20];
    const float* bw    = (const float*)d_in[21];
    const int* qseq    = (const int*)d_in[22];
    const int* cseq    = (const int*)d_in[23];
    const int* mseq    = (const int*)d_in[24];
    const int* qtab    = (const int*)d_in[25];
    float* out = (float*)d_out;

    char* p = (char*)d_ws;
    auto alloc = [&](size_t bytes) { char* r = p; p += alup(bytes); return r; };
    int*   cnt    = (int*)  alloc(4096);
    int*   fill   = (int*)  alloc(4096);               // contiguous with cnt
    int*   offs   = (int*)  alloc(1001*4);
    int*   edge_q = (int*)  alloc((size_t)NEz*4);
    float* m2     = (float*)alloc((size_t)NCz*128*4);
    float* T1     = (float*)alloc(128*128*4);
    float* T2     = (float*)alloc(128*128*4);
    float* Mt     = (float*)alloc(128*128*4);
    float* gr     = (float*)alloc(2*384*4);
    float* Bkq    = (float*)alloc(132*128*4);
    float* biaskq = (float*)alloc(132*4);
    float* eq     = (float*)alloc((size_t)NSz*128*4);
    float* gi1    = (float*)alloc((size_t)NSz*384*4);
    float* stateh = (float*)alloc((size_t)NSz*128*4);
    float* kqt    = (float*)alloc((size_t)Bz*132*KTpad*4);   // transposed kq operand
    // aliases: eq is dead after the gi1 GEMM -> reuse as h1 sequence;
    //          gi1 is dead after scan1 -> reuse as gi2.
    float* h1all = eq;
    float* gi2   = gi1;

    hipMemsetAsync(cnt, 0, 8192, stream);                       // cnt + fill
    hipMemsetAsync(d_out, 0, (size_t)out_size*4, stream);       // y[:,0] = 0

    k_count<<<(NEz+255)/256, 256, 0, stream>>>(qtab, cnt);
    k_offs <<<1, 1024, 0, stream>>>(cnt, offs);
    k_fill <<<(NEz+255)/256, 256, 0, stream>>>(qtab, offs, fill, edge_q);
    k_m2   <<<NCz, 512, 0, stream>>>(qtab, offs, edge_q, emb_q, emb_c, m2);

    k_mm128<false><<<128, 128, 0, stream>>>(Wg2, Wg1, T1);      // T1 = Wg2*Wg1
    k_mm128<false><<<128, 128, 0, stream>>>(Wg3, T1, T2);       // T2 = Wg3*T1
    k_mm128<true> <<<128, 128, 0, stream>>>(Wagg, T2, Mt);      // Mt = (Wagg*T2)^T
    k_gr  <<<1, 768, 0, stream>>>(emb_r, Wih1, bih1, gr);
    k_bkq <<<130, 128, 0, stream>>>(Wq, Wk, bq, bk, Ww, bw, Bkq, biaskq);

    k_eq  <<<NSz/16, 256, 0, stream>>>(Mt, bagg, emb_q, emb_c, m2, qseq, mseq, qtab, eq);

    // gi1 = eq @ Wih1[:, :128]^T + gr[r_t]   (input gates, layer 1)  [bf16-dot2]
    k_gemm<1,1><<<dim3(NSz/64, 6), dim3(16,16), 0, stream>>>(eq, Wih1, 256, 384,
                                                             gi1, 384, nullptr, gr, cseq);
    // layer-1 scan (Whh1 only) -> h1 sequence (overwrites eq)
    k_scan<<<Bz, 512, 0, stream>>>(gi1, Whh1, bhh1, h1all);
    // gi2 = h1 @ Wih2^T + bih2  (input gates, layer 2; overwrites gi1)  [bf16-dot2]
    k_gemm<0,1><<<dim3(NSz/64, 6), dim3(16,16), 0, stream>>>(h1all, Wih2, 128, 384,
                                                             gi2, 384, bih2, nullptr, nullptr);
    // layer-2 scan (Whh2 only) -> h2 sequence
    k_scan<<<Bz, 512, 0, stream>>>(gi2, Whh2, bhh2, stateh);

    // kqt: fp32 path, TRANSPOSED store (attention scores / top-k ordering untouched)
    k_gemm<2,0><<<dim3(NSz/64, 3), dim3(16,16), 0, stream>>>(stateh, Bkq, 128, 132,
                                                             kqt, 0, biaskq, nullptr, nullptr);
    k_attn<<<dim3((Tz+3)/4, Bz), 256, 0, stream>>>(kqt, qseq, qtab, emb_q, emb_c, Ww, out);
}